// Round 11
// baseline (402.430 us; speedup 1.0000x reference)
//
#include <hip/hip_runtime.h>
#include <hip/hip_bf16.h>
#include <math.h>

#define L     16384
#define IMG   128
#define BATCH 2
#define C0    192
#define NH    4
#define CHN   48
#define HID   510
#define HID2  1020
#define BL    (BATCH*L)
#define KSPLIT 256

typedef float  f32x4  __attribute__((ext_vector_type(4)));
typedef __bf16 bf16x8 __attribute__((ext_vector_type(8)));

union UB16 { uint4 u; bf16x8 v; };

__device__ __forceinline__ bf16x8 ld_bf8(const ushort* p){ UB16 x; x.u = *(const uint4*)p; return x.v; }
__device__ __forceinline__ f32x4 mfma16(bf16x8 a, bf16x8 b, f32x4 c){
  return __builtin_amdgcn_mfma_f32_16x16x32_bf16(a, b, c, 0, 0, 0);
}
__device__ __forceinline__ float u2f(ushort u){ union{unsigned u; float f;} x; x.u = ((unsigned)u)<<16; return x.f; }
__device__ __forceinline__ ushort f2u(float f){ __hip_bfloat16 h = __float2bfloat16(f); return *reinterpret_cast<ushort*>(&h); }
__device__ __forceinline__ float gelu_exact(float x){ return 0.5f*x*(1.0f+erff(x*0.70710678118654752f)); }

// ---------------- LN stats + frag-packed bf16 mirror (for lr, ref) ----------------
__global__ __launch_bounds__(256) void ln_stats3_k(const float* __restrict__ x,
                                                   float* __restrict__ mu, float* __restrict__ rsig,
                                                   ushort* __restrict__ xf){
  int pos = blockIdx.x*256 + threadIdx.x;
  int b = pos >> 14, l = pos & (L-1);
  const float* xp = x + (size_t)b*C0*L + l;
  ushort* base = xf + (size_t)b*C0*L;
  int pt = l >> 4, c16 = l & 15;
  float s=0.f, ss=0.f;
  #pragma unroll
  for (int st=0; st<6; ++st)
    #pragma unroll
    for (int g=0; g<4; ++g){
      ushort u8[8];
      #pragma unroll
      for (int j=0;j<8;++j){
        float v = xp[(size_t)(st*32 + g*8 + j)*L];
        s += v; ss += v*v; u8[j] = f2u(v);
      }
      *(uint4*)(base + ((size_t)(pt*6+st)*64 + g*16 + c16)*8) = *(const uint4*)u8;
    }
  float m = s*(1.f/C0);
  float var = ss*(1.f/C0) - m*m;
  mu[pos]=m; rsig[pos]=rsqrtf(var + 1e-5f);
}

__global__ void finln_k(const float* __restrict__ sum, const float* __restrict__ ss,
                        float* __restrict__ mu, float* __restrict__ rs){
  int i = blockIdx.x*256 + threadIdx.x;
  float m = sum[i]*(1.f/C0);
  float v = ss[i]*(1.f/C0) - m*m;
  mu[i] = m; rs[i] = rsqrtf(v + 1e-5f);
}

// ---------------- weight packing: MFMA-fragment order ----------------
__global__ void packwf_k(const float* __restrict__ W, const float* __restrict__ lnw,
                         ushort* __restrict__ out, int Csrc, int O, int KS, int total){
  int idx = blockIdx.x*256 + threadIdx.x;
  if (idx >= total) return;
  int j = idx & 7; int t = idx >> 3;
  int lane = t & 63; t >>= 6;
  int st = t % KS; int mt = t / KS;
  int m = mt*16 + (lane & 15);
  int k = st*32 + (lane >> 4)*8 + j;
  float v = 0.f;
  if (m < O && k < Csrc){ v = W[(size_t)m*Csrc + k]; if (lnw) v *= lnw[k]; }
  out[idx] = f2u(v);
}

__global__ void prepab_k(const float* __restrict__ W, const float* __restrict__ lnw,
                         const float* __restrict__ lnb, float* __restrict__ A, float* __restrict__ Bv,
                         int Cc, int O, int Opad){
  int o = blockIdx.x*256 + threadIdx.x;
  if (o >= Opad) return;
  float a=0.f,b=0.f;
  if (o < O){
    const float* wr = W + (size_t)o*Cc;
    for (int c=0;c<Cc;++c){ float w=wr[c]; a = fmaf(w, lnw[c], a); b = fmaf(w, lnb[c], b); }
  }
  A[o]=a; Bv[o]=b;
}

// ---------------- gemm5: barrier-free streaming MFMA GEMM ----------------
// WR=2: 128xBN tile (4 waves 2x2). WR=1: 64xBN tile (4 waves, BN/4 cols each).
// EPI 0: LN bf16 out (two-pass 64-row LDS bounce); EPI 2: f32 out+=acc;
// EPI 3: f32 out=res+acc AND bf16 frag-packed outf AND per-position sum/ss atomics (WR=1,BN=128)
template<int EPI, int WR, int KS, int BN>
__global__ __launch_bounds__(256, WR==2?4:5) void gemm5_k(
    const ushort* __restrict__ Af, int aBS,
    const ushort* __restrict__ Xf, size_t xBS,
    const float* __restrict__ mu, const float* __restrict__ rs,
    const float* __restrict__ Avec, const float* __restrict__ Bvec,
    const float* __restrict__ res,
    void* __restrict__ outp, int Orows, int Ovalid,
    ushort* __restrict__ outf, float* __restrict__ sum_acc, float* __restrict__ ss_acc)
{
  constexpr int BM  = WR*64;
  constexpr int NF  = (WR==2) ? 4 : (BN/64);
  constexpr int PB  = L/BN;
  constexpr int BLD = BN+8;
  constexpr int NSH = (EPI==0)? 64*BLD : (EPI==3 ? BN*72 : 64);
  __shared__ ushort bb[NSH];

  const int tid=threadIdx.x, lane=tid&63, w=tid>>6;
  const int g16=lane>>4, c16=lane&15;
  const int cpx = gridDim.x>>3;
  const int p = (blockIdx.x&7)*cpx + (blockIdx.x>>3);   // XCD-bijective
  const int b = p / PB;
  const int l0 = (p - b*PB)*BN;
  const int mbase = blockIdx.y*BM;
  const int wr = (WR==2)? (w>>1)*64 : 0;
  const int wc = (WR==2)? (w&1)*64 : w*(BN/4);
  const int mt0 = (mbase+wr)>>4;
  const int pt0 = (l0+wc)>>4;

  const ushort* Ap = Af + (size_t)b*aBS + ((size_t)(mt0*KS)*64 + lane)*8;
  const ushort* Bp = Xf + (size_t)b*xBS + ((size_t)(pt0*KS)*64 + lane)*8;

  f32x4 acc[4][NF];
  #pragma unroll
  for (int mi=0;mi<4;++mi)
    #pragma unroll
    for (int ni=0;ni<NF;++ni){ f32x4 z={0.f,0.f,0.f,0.f}; acc[mi][ni]=z; }

  bf16x8 ar[2][4], br[2][NF];
  #pragma unroll
  for (int i=0;i<4;++i) ar[0][i] = ld_bf8(Ap + (size_t)(i*KS)*512);
  #pragma unroll
  for (int i=0;i<NF;++i) br[0][i] = ld_bf8(Bp + (size_t)(i*KS)*512);
  #pragma unroll
  for (int st=0; st<KS; ++st){
    const int cur = st&1, nxt = cur^1;
    if (st+1 < KS){
      #pragma unroll
      for (int i=0;i<4;++i)  ar[nxt][i] = ld_bf8(Ap + (size_t)(i*KS + st+1)*512);
      #pragma unroll
      for (int i=0;i<NF;++i) br[nxt][i] = ld_bf8(Bp + (size_t)(i*KS + st+1)*512);
    }
    #pragma unroll
    for (int mi=0;mi<4;++mi)
      #pragma unroll
      for (int ni=0;ni<NF;++ni)
        acc[mi][ni] = mfma16(ar[cur][mi], br[cur][ni], acc[mi][ni]);
  }

  if (EPI==0){
    constexpr int SEG = BN/64;
    #pragma unroll
    for (int half=0; half<WR; ++half){
      if (half) __syncthreads();
      if (WR==1 || wr == half*64){
        #pragma unroll
        for (int ni=0;ni<NF;++ni){
          int nl = wc + ni*16 + c16;
          int posl = b*L + l0 + nl;
          float muv = mu[posl], rsv = rs[posl];
          #pragma unroll
          for (int mi=0;mi<4;++mi)
            #pragma unroll
            for (int r=0;r<4;++r){
              int rl = mi*16 + g16*4 + r;          // local row 0..63
              int o  = mbase + wr + rl;
              bb[rl*BLD + nl] = f2u(rsv*(acc[mi][ni][r] - muv*Avec[o]) + Bvec[o]);
            }
        }
      }
      __syncthreads();
      if (tid < 64*SEG){
        int row = tid/SEG, seg = tid%SEG;
        int orow = mbase + half*64 + row;
        if (orow < Ovalid){
          ushort* dst = (ushort*)outp + ((size_t)b*Orows + orow)*L + l0 + seg*64;
          const ushort* src = &bb[row*BLD + seg*64];
          #pragma unroll
          for (int i=0;i<8;++i) *(uint4*)(dst + i*8) = *(const uint4*)(src + i*8);
        }
      }
    }
  } else if (EPI==3){
    #pragma unroll
    for (int ni=0;ni<NF;++ni){
      int nl = wc + ni*16 + c16;
      int posl = b*L + l0 + nl;
      size_t cbase = ((size_t)b*Orows + mbase)*L + l0 + nl;
      float s1=0.f, s2=0.f;
      #pragma unroll
      for (int mi=0;mi<4;++mi)
        #pragma unroll
        for (int r=0;r<4;++r){
          int ro = mi*16 + g16*4 + r;
          size_t idx = cbase + (size_t)ro*L;
          float v = res[idx] + acc[mi][ni][r];
          ((float*)outp)[idx] = v;
          s1 += v; s2 += v*v;
          bb[nl*72 + ro] = f2u(v);
        }
      s1 += __shfl_xor(s1,16,64); s1 += __shfl_xor(s1,32,64);
      s2 += __shfl_xor(s2,16,64); s2 += __shfl_xor(s2,32,64);
      if (g16==0){ atomicAdd(&sum_acc[posl], s1); atomicAdd(&ss_acc[posl], s2); }
    }
    __syncthreads();
    constexpr int PTS = BN/16;
    int ph  = tid >> 7;
    int rm  = tid & 127;
    int stl = rm >> 6;
    int gf  = (rm >> 4) & 3;
    int cf  = rm & 15;
    int stg = (mbase >> 5) + stl;
    #pragma unroll
    for (int pp=0; pp<PTS/2; ++pp){
      int ptl = ph*(PTS/2) + pp;
      int nl  = ptl*16 + cf;
      uint4 v = *(const uint4*)&bb[nl*72 + stl*32 + gf*8];
      int ptg = (l0 >> 4) + ptl;
      *(uint4*)(outf + (size_t)b*C0*L + ((size_t)(ptg*6 + stg)*64 + gf*16 + cf)*8) = v;
    }
  } else {
    #pragma unroll
    for (int ni=0;ni<NF;++ni){
      int nl = wc + ni*16 + c16;
      #pragma unroll
      for (int mi=0;mi<4;++mi)
        #pragma unroll
        for (int r=0;r<4;++r){
          int o = mbase + wr + mi*16 + g16*4 + r;
          size_t idx = ((size_t)b*Orows + o)*L + l0 + nl;
          ((float*)outp)[idx] += acc[mi][ni][r];
        }
    }
  }
}

// ---------------- depthwise 3x3, 8 px/thread, row-major out, sum-of-squares ----------------
__global__ __launch_bounds__(256) void dwconv8_k(const ushort* __restrict__ in, const float* __restrict__ w9,
    ushort* __restrict__ out, float* __restrict__ ss, int Cc, size_t inBS, size_t outBS){
  int e  = blockIdx.x*256 + threadIdx.x;
  int bc = e >> 11;
  int p  = (e & 2047) * 8;
  int c  = bc % Cc, b = bc / Cc;
  int y  = p >> 7, x0 = p & 127;
  const ushort* ip = in + (size_t)b*inBS + (size_t)c*L;
  float w[9];
  #pragma unroll
  for (int i=0;i<9;++i) w[i] = w9[c*9+i];
  float v[3][10];
  #pragma unroll
  for (int r=0;r<3;++r){
    int yy = y + r - 1;
    if ((unsigned)yy >= IMG){
      #pragma unroll
      for (int j=0;j<10;++j) v[r][j]=0.f;
    } else {
      const ushort* rp = ip + yy*IMG + x0;
      uint4 cv = *(const uint4*)rp; const ushort* us = (const ushort*)&cv;
      #pragma unroll
      for (int j=0;j<8;++j) v[r][j+1] = u2f(us[j]);
      v[r][0] = (x0>0)   ? u2f(rp[-1]) : 0.f;
      v[r][9] = (x0<120) ? u2f(rp[8])  : 0.f;
    }
  }
  float sq = 0.f; ushort o8[8];
  #pragma unroll
  for (int j=0;j<8;++j){
    float a = 0.f;
    #pragma unroll
    for (int r=0;r<3;++r)
      #pragma unroll
      for (int dx=0;dx<3;++dx) a = fmaf(w[r*3+dx], v[r][j+dx], a);
    o8[j] = f2u(a); sq += a*a;
  }
  *(uint4*)(out + (size_t)b*outBS + (size_t)c*L + p) = *(const uint4*)o8;
  #pragma unroll
  for (int off=32; off>0; off>>=1) sq += __shfl_xor(sq, off, 64);
  __shared__ float red[4];
  int wid = threadIdx.x >> 6;
  if ((threadIdx.x & 63)==0) red[wid]=sq;
  __syncthreads();
  if (threadIdx.x==0) atomicAdd(&ss[b*Cc + c], red[0]+red[1]+red[2]+red[3]);
}

// ---------------- depthwise 3x3 for v-rows, frag-packed out, XCD-swizzled, XOR-LDS ----------------
__global__ __launch_bounds__(256) void dwconvV_k(const ushort* __restrict__ in, const float* __restrict__ w9,
                                                 ushort* __restrict__ vf){
  __shared__ ushort lt[64][40];
  int xs = blockIdx.x;
  int chunk = ((xs & 7) << 5) | (xs >> 3);        // XCD-contiguous y-slices
  int st = blockIdx.y, b = blockIdx.z;
  int t = threadIdx.x;
  int c = t >> 3, xo = (t & 7)*8;
  int l0 = chunk*64;
  int y = l0 >> 7, px = (l0 & 127) + xo;
  int gc = st*32 + c;
  const ushort* ip = in + ((size_t)b*384 + C0 + gc)*L;
  const float* wp = w9 + (size_t)(C0+gc)*9;
  float w[9];
  #pragma unroll
  for (int i=0;i<9;++i) w[i] = wp[i];
  float v[3][10];
  #pragma unroll
  for (int r=0;r<3;++r){
    int yy = y + r - 1;
    if ((unsigned)yy >= IMG){
      #pragma unroll
      for (int j=0;j<10;++j) v[r][j]=0.f;
    } else {
      const ushort* rp = ip + yy*IMG + px;
      uint4 cv = *(const uint4*)rp; const ushort* us = (const ushort*)&cv;
      #pragma unroll
      for (int j=0;j<8;++j) v[r][j+1] = u2f(us[j]);
      v[r][0] = (px>0)   ? u2f(rp[-1]) : 0.f;
      v[r][9] = (px<120) ? u2f(rp[8])  : 0.f;
    }
  }
  #pragma unroll
  for (int j=0;j<8;++j){
    float a = 0.f;
    #pragma unroll
    for (int r=0;r<3;++r)
      #pragma unroll
      for (int dx=0;dx<3;++dx) a = fmaf(w[r*3+dx], v[r][j+dx], a);
    int row = xo + j;
    lt[row][c ^ (((row>>3)&3)<<3)] = f2u(a);
  }
  __syncthreads();
  int ptl = t>>6, gf = (t>>4)&3, cf = t&15;
  int rrow = ptl*16 + cf;
  int oct = gf ^ ((rrow>>3)&3);
  uint4 vv = *(const uint4*)&lt[rrow][oct*8];
  int pt = (l0>>4) + ptl;
  *(uint4*)(vf + (size_t)b*C0*L + ((size_t)(pt*6 + st)*64 + gf*16 + cf)*8) = vv;
}

// ---------------- QK^T via MFMA, k-split over L ----------------
__global__ __launch_bounds__(64) void qk_mfma_k(const ushort* __restrict__ qb, const ushort* __restrict__ kb,
                                                float* __restrict__ P){
  int ks = blockIdx.x, bh = blockIdx.y;
  int b = bh >> 2, h = bh & 3;
  int lane = threadIdx.x, g16 = lane>>4, c16 = lane&15;
  const ushort* qbase = qb + ((size_t)b*C0 + h*CHN)*L;
  const ushort* kbse  = kb + ((size_t)b*C0 + h*CHN)*L;
  f32x4 acc[3][3];
  #pragma unroll
  for (int i=0;i<3;++i)
    #pragma unroll
    for (int j=0;j<3;++j){ f32x4 z={0.f,0.f,0.f,0.f}; acc[i][j]=z; }
  int k0 = ks * (L/KSPLIT);
  for (int kk=0; kk<(L/KSPLIT)/32; ++kk){
    int kb2 = k0 + kk*32;
    bf16x8 af[3], bv[3];
    #pragma unroll
    for (int i=0;i<3;++i){
      af[i] = ld_bf8(qbase + (size_t)(i*16+c16)*L + kb2 + g16*8);
      bv[i] = ld_bf8(kbse  + (size_t)(i*16+c16)*L + kb2 + g16*8);
    }
    #pragma unroll
    for (int mi=0;mi<3;++mi)
      #pragma unroll
      for (int ni=0;ni<3;++ni)
        acc[mi][ni] = mfma16(af[mi], bv[ni], acc[mi][ni]);
  }
  float* Pp = P + ((size_t)ks*(BATCH*NH) + bh)*CHN*CHN;
  #pragma unroll
  for (int mi=0;mi<3;++mi)
    #pragma unroll
    for (int ni=0;ni<3;++ni)
      #pragma unroll
      for (int r=0;r<4;++r){
        int m = mi*16 + g16*4 + r, n = ni*16 + c16;
        Pp[m*CHN + n] = acc[mi][ni][r];
      }
}

__global__ void reduceS_k(const float* __restrict__ P, float* __restrict__ S){
  int i = blockIdx.x*256 + threadIdx.x;
  if (i >= BATCH*NH*CHN*CHN) return;
  float s = 0.f;
  for (int ks=0; ks<KSPLIT; ++ks) s += P[(size_t)ks*(BATCH*NH*CHN*CHN) + i];
  S[i] = s;
}

// ---------------- softmax + gating + Wca modulation ----------------
__global__ __launch_bounds__(64) void gating_k(const float* __restrict__ S, const float* __restrict__ qss,
                         const float* __restrict__ kss, const float* __restrict__ temp,
                         const float* __restrict__ Wca, float* __restrict__ attnF){
  int blk = blockIdx.x;
  int c  = blk % CHN; int bh = blk / CHN;
  int h  = bh & 3, b = bh >> 2;
  int d  = threadIdx.x;
  bool act = (d < CHN);

  float T  = temp[h];
  float nq = sqrtf(qss[b*C0 + h*CHN + c]);
  float rq = 1.f/fmaxf(nq, 1e-12f);
  float rk = 0.f, sv = 0.f;
  if (act){
    float nk = sqrtf(kss[b*C0 + h*CHN + d]);
    rk = 1.f/fmaxf(nk, 1e-12f);
    sv = S[((size_t)bh*CHN + c)*CHN + d];
  }
  float raw = act ? sv*rq*rk*T : -1e30f;

  float mx = raw;
  #pragma unroll
  for (int off=32; off>0; off>>=1) mx = fmaxf(mx, __shfl_xor(mx, off, 64));
  float e = act ? expf(raw - mx) : 0.f;
  float sum = e;
  #pragma unroll
  for (int off=32; off>0; off>>=1) sum += __shfl_xor(sum, off, 64);
  float a0 = e / sum;

  float r = fmaxf(raw, 0.f); r = r*r;
  float a1 = gelu_exact(r)*r;
  __shared__ float a1s[CHN];
  if (act) a1s[d] = a1;
  __syncthreads();

  if (!act) return;
  float s1 = 0.f, s2 = 0.f;
  const float* w1 = Wca + (size_t)d*CHN;
  const float* w2 = Wca + (size_t)(d+CHN)*CHN;
  #pragma unroll
  for (int j=0;j<CHN;++j){
    float aj = a1s[j];
    s1 = fmaf(w1[j], aj, s1);
    s2 = fmaf(w2[j], aj, s2);
  }
  attnF[((size_t)bh*CHN + c)*CHN + d] = a0*(1.f+s1) + s2;
}

// Mtf frag-packed
__global__ void mtf_k(const float* __restrict__ Wproj, const float* __restrict__ attnF,
                      ushort* __restrict__ Mtf){
  int idx = blockIdx.x*256 + threadIdx.x;
  if (idx >= BATCH*192*192) return;
  int j = idx & 7; int t = idx >> 3;
  int lane = t & 63; t >>= 6;
  int st = t % 6; t /= 6;
  int mt = t % 12; int b = t / 12;
  int o = mt*16 + (lane & 15);
  int d = st*32 + (lane >> 4)*8 + j;
  int h = d / CHN, dd = d % CHN;
  float s=0.f;
  for (int c=0;c<CHN;++c)
    s = fmaf(Wproj[(size_t)o*C0 + h*CHN + c],
             attnF[(((size_t)(b*NH+h))*CHN + c)*CHN + dd], s);
  Mtf[idx] = f2u(s);
}

// ---------------- GDFN dwconv + gelu gate -> frag-packed Gf, XCD-swizzled, XOR-LDS ----------------
__global__ __launch_bounds__(256) void ffn8f_k(const ushort* __restrict__ hidden, const float* __restrict__ w9,
                                               ushort* __restrict__ gf){
  __shared__ ushort lt[64][40];
  int xs = blockIdx.x;
  int chunk = ((xs & 7) << 5) | (xs >> 3);        // XCD-contiguous y-slices
  int st = blockIdx.y, b = blockIdx.z;
  int t = threadIdx.x;
  int c = t >> 3, xo = (t & 7)*8;
  int l0 = chunk*64;
  int y = l0 >> 7, px = (l0 & 127) + xo;
  int gc = st*32 + c;
  ushort o8[8];
  if (gc < HID){
    const ushort* i1 = hidden + ((size_t)b*HID2 + gc)*L;
    const ushort* i2 = i1 + (size_t)HID*L;
    float w1[9], w2[9];
    #pragma unroll
    for (int i=0;i<9;++i){ w1[i] = w9[gc*9+i]; w2[i] = w9[(HID+gc)*9+i]; }
    float v1[3][10], v2[3][10];
    #pragma unroll
    for (int r=0;r<3;++r){
      int yy = y + r - 1;
      if ((unsigned)yy >= IMG){
        #pragma unroll
        for (int j=0;j<10;++j){ v1[r][j]=0.f; v2[r][j]=0.f; }
      } else {
        const ushort* rp1 = i1 + yy*IMG + px;
        const ushort* rp2 = i2 + yy*IMG + px;
        uint4 c1 = *(const uint4*)rp1; const ushort* u1 = (const ushort*)&c1;
        uint4 c2 = *(const uint4*)rp2; const ushort* u2 = (const ushort*)&c2;
        #pragma unroll
        for (int j=0;j<8;++j){ v1[r][j+1] = u2f(u1[j]); v2[r][j+1] = u2f(u2[j]); }
        v1[r][0] = (px>0)   ? u2f(rp1[-1]) : 0.f;
        v1[r][9] = (px<120) ? u2f(rp1[8])  : 0.f;
        v2[r][0] = (px>0)   ? u2f(rp2[-1]) : 0.f;
        v2[r][9] = (px<120) ? u2f(rp2[8])  : 0.f;
      }
    }
    #pragma unroll
    for (int j=0;j<8;++j){
      float d1=0.f, d2=0.f;
      #pragma unroll
      for (int r=0;r<3;++r)
        #pragma unroll
        for (int dx=0;dx<3;++dx){
          d1 = fmaf(w1[r*3+dx], v1[r][j+dx], d1);
          d2 = fmaf(w2[r*3+dx], v2[r][j+dx], d2);
        }
      o8[j] = f2u(gelu_exact(d1)*d2);
    }
  } else {
    #pragma unroll
    for (int j=0;j<8;++j) o8[j] = 0;
  }
  #pragma unroll
  for (int j=0;j<8;++j){
    int row = xo + j;
    lt[row][c ^ (((row>>3)&3)<<3)] = o8[j];
  }
  __syncthreads();
  int ptl = t>>6, gfr = (t>>4)&3, cf = t&15;
  int rrow = ptl*16 + cf;
  int oct = gfr ^ ((rrow>>3)&3);
  uint4 vv = *(const uint4*)&lt[rrow][oct*8];
  int pt = (l0>>4) + ptl;
  *(uint4*)(gf + (size_t)b*512*L + ((size_t)(pt*16 + st)*64 + gfr*16 + cf)*8) = vv;
}

extern "C" void kernel_launch(void* const* d_in, const int* in_sizes, int n_in,
                              void* d_out, int out_size, void* d_ws, size_t ws_size,
                              hipStream_t stream){
  (void)in_sizes; (void)n_in; (void)out_size; (void)ws_size;
  const float* lr    = (const float*)d_in[0];
  const float* ref   = (const float*)d_in[1];
  const float* ln1w  = (const float*)d_in[2];
  const float* ln1b  = (const float*)d_in[3];
  const float* lnrw  = (const float*)d_in[4];
  const float* lnrb  = (const float*)d_in[5];
  const float* ln2w  = (const float*)d_in[6];
  const float* ln2b  = (const float*)d_in[7];
  const float* Wq    = (const float*)d_in[8];
  const float* qdw   = (const float*)d_in[9];
  const float* Wkv   = (const float*)d_in[10];
  const float* kvdw  = (const float*)d_in[11];
  const float* Wproj = (const float*)d_in[12];
  const float* Wca   = (const float*)d_in[13];
  const float* temp  = (const float*)d_in[14];
  const float* Wpin  = (const float*)d_in[15];
  const float* ffndw = (const float*)d_in[16];
  const float* Wpout = (const float*)d_in[17];
  float* out = (float*)d_out;

  char* ws = (char*)d_ws;
  size_t off = 0;
  auto alloc = [&](size_t bytes)->void*{ void* p = ws + off; off += (bytes + 255) & ~(size_t)255; return p; };

  ushort* Aqf    = (ushort*)alloc((size_t)192*192*2);
  ushort* Akvf   = (ushort*)alloc((size_t)384*192*2);
  ushort* Apinf  = (ushort*)alloc((size_t)1024*192*2);
  ushort* Apoutf = (ushort*)alloc((size_t)192*512*2);
  ushort* Mtf    = (ushort*)alloc((size_t)BATCH*192*192*2);
  float* Aqv  = (float*)alloc(192*4);   float* Bqv  = (float*)alloc(192*4);
  float* Akvv = (float*)alloc(384*4);   float* Bkvv = (float*)alloc(384*4);
  float* Apinv= (float*)alloc(1024*4);  float* Bpinv= (float*)alloc(1024*4);
  float* mu_lr = (float*)alloc((size_t)BL*4);  float* rs_lr = (float*)alloc((size_t)BL*4);
  float* mu_rf = (float*)alloc((size_t)BL*4);  float* rs_rf = (float*)alloc((size_t)BL*4);
  float* mu_o  = (float*)alloc((size_t)BL*4);  float* rs_o  = (float*)alloc((size_t)BL*4);
  float* sum_o = (float*)alloc((size_t)BL*4);  float* ssq_o = (float*)alloc((size_t)BL*4);
  float* qss   = (float*)alloc((size_t)BATCH*C0*4);
  float* kss   = (float*)alloc((size_t)BATCH*C0*4);
  float* S     = (float*)alloc((size_t)BATCH*NH*CHN*CHN*4);
  float* attnF = (float*)alloc((size_t)BATCH*NH*CHN*CHN*4);
  char*  pool  = (char*)alloc((size_t)104857600);

  // region map (sequential reuse):
  ushort* LRf    = (ushort*)(pool);                    // [0, 12.6M)
  ushort* REFf   = (ushort*)(pool + 12582912);         // [12.6, 25.2)
  ushort* q_pre  = (ushort*)(pool + 25165824);         // [25.2, 37.8)
  ushort* kv_pre = (ushort*)(pool + 37748736);         // [37.8, 63.0)
  ushort* qb     = (ushort*)(pool + 62914560);         // [63.0, 75.6)
  ushort* kvb_k  = (ushort*)(pool + 75497472);         // [75.6, 88.1)  k-rows only
  ushort* Vf     = (ushort*)(pool + 88080384);         // [88.1, 100.7) frag-packed v
  float*  Pp     = (float*) (pool);                    // 18.9M over LRf+REFf
  ushort* OUTf   = (ushort*)(pool);                    // 12.6M over Pp
  ushort* hidden = (ushort*)(pool + 33554432);         // 66.8M over kv_pre..Vf
  ushort* Gf     = (ushort*)(pool);                    // 33.5M over OUTf+REFf+q_pre

  hipMemsetAsync(qss, 0, (size_t)BATCH*C0*4, stream);
  hipMemsetAsync(kss, 0, (size_t)BATCH*C0*4, stream);
  hipMemsetAsync(sum_o, 0, (size_t)BL*4, stream);
  hipMemsetAsync(ssq_o, 0, (size_t)BL*4, stream);

  // weight prep (frag-packed)
  packwf_k<<<144,256,0,stream>>>(Wq,   ln1w, Aqf,   192, 192, 6, 192*192);
  packwf_k<<<288,256,0,stream>>>(Wkv,  lnrw, Akvf,  192, 384, 6, 384*192);
  packwf_k<<<768,256,0,stream>>>(Wpin, ln2w, Apinf, 192, 1020, 6, 1024*192);
  packwf_k<<<384,256,0,stream>>>(Wpout, nullptr, Apoutf, 510, 192, 16, 192*512);
  prepab_k<<<1,256,0,stream>>>(Wq,  ln1w, ln1b, Aqv,  Bqv,  192, 192, 192);
  prepab_k<<<2,256,0,stream>>>(Wkv, lnrw, lnrb, Akvv, Bkvv, 192, 384, 384);
  prepab_k<<<4,256,0,stream>>>(Wpin,ln2w, ln2b, Apinv,Bpinv,192, 1020, 1024);

  // LN stats + frag-packed mirrors
  ln_stats3_k<<<BL/256,256,0,stream>>>(lr,  mu_lr, rs_lr, LRf);
  ln_stats3_k<<<BL/256,256,0,stream>>>(ref, mu_rf, rs_rf, REFf);

  // fused LN + 1x1 conv GEMMs
  gemm5_k<0,1,6,128><<<dim3(256,3),256,0,stream>>>(Aqf, 0, LRf, (size_t)C0*L,
      mu_lr, rs_lr, Aqv, Bqv, nullptr, q_pre, 192, 192, nullptr, nullptr, nullptr);
  gemm5_k<0,2,6,128><<<dim3(256,3),256,0,stream>>>(Akvf, 0, REFf, (size_t)C0*L,
      mu_rf, rs_rf, Akvv, Bkvv, nullptr, kv_pre, 384, 384, nullptr, nullptr, nullptr);

  // depthwise convs: q and k row-major (+ss), v direct frag-packed
  dwconv8_k<<<3072,256,0,stream>>>(q_pre,  qdw,  qb,    qss, 192, (size_t)192*L, (size_t)192*L);
  dwconv8_k<<<3072,256,0,stream>>>(kv_pre, kvdw, kvb_k, kss, 192, (size_t)384*L, (size_t)192*L);
  dwconvV_k<<<dim3(256,6,2),256,0,stream>>>(kv_pre, kvdw, Vf);

  // attention core
  qk_mfma_k<<<dim3(KSPLIT, BATCH*NH),64,0,stream>>>(qb, kvb_k, Pp);
  reduceS_k<<<(BATCH*NH*CHN*CHN+255)/256,256,0,stream>>>(Pp, S);
  gating_k<<<BATCH*NH*CHN,64,0,stream>>>(S, qss, kss, temp, Wca, attnF);
  mtf_k<<<288,256,0,stream>>>(Wproj, attnF, Mtf);

  // out = lr + Mt.v  (+ frag-packed OUTf + LN-stat atomics fused)
  gemm5_k<3,1,6,128><<<dim3(256,3),256,0,stream>>>(Mtf, 192*192, Vf, (size_t)C0*L,
      nullptr, nullptr, nullptr, nullptr, lr, out, 192, 192, OUTf, sum_o, ssq_o);
  finln_k<<<BL/256,256,0,stream>>>(sum_o, ssq_o, mu_o, rs_o);

  // GDFN
  gemm5_k<0,2,6,128><<<dim3(256,8),256,0,stream>>>(Apinf, 0, OUTf, (size_t)C0*L,
      mu_o, rs_o, Apinv, Bpinv, nullptr, hidden, 1020, 1020, nullptr, nullptr, nullptr);
  ffn8f_k<<<dim3(256,16,2),256,0,stream>>>(hidden, ffndw, Gf);
  gemm5_k<2,1,16,128><<<dim3(256,3),256,0,stream>>>(Apoutf, 0, Gf, (size_t)512*L,
      nullptr, nullptr, nullptr, nullptr, nullptr, out, 192, 192, nullptr, nullptr, nullptr);
}

// Round 12
// 360.046 us; speedup vs baseline: 1.1177x; 1.1177x over previous
//
#include <hip/hip_runtime.h>
#include <hip/hip_bf16.h>
#include <math.h>

#define L     16384
#define IMG   128
#define BATCH 2
#define C0    192
#define NH    4
#define CHN   48
#define HID   510
#define HID2  1020
#define BL    (BATCH*L)
#define KSPLIT 256

typedef float  f32x4  __attribute__((ext_vector_type(4)));
typedef __bf16 bf16x8 __attribute__((ext_vector_type(8)));

union UB16 { uint4 u; bf16x8 v; };

__device__ __forceinline__ bf16x8 ld_bf8(const ushort* p){ UB16 x; x.u = *(const uint4*)p; return x.v; }
__device__ __forceinline__ f32x4 mfma16(bf16x8 a, bf16x8 b, f32x4 c){
  return __builtin_amdgcn_mfma_f32_16x16x32_bf16(a, b, c, 0, 0, 0);
}
__device__ __forceinline__ float u2f(ushort u){ union{unsigned u; float f;} x; x.u = ((unsigned)u)<<16; return x.f; }
__device__ __forceinline__ ushort f2u(float f){ __hip_bfloat16 h = __float2bfloat16(f); return *reinterpret_cast<ushort*>(&h); }
__device__ __forceinline__ float gelu_exact(float x){ return 0.5f*x*(1.0f+erff(x*0.70710678118654752f)); }

// ---------------- LN stats + frag-packed bf16 mirror (for lr, ref) ----------------
__global__ __launch_bounds__(256) void ln_stats3_k(const float* __restrict__ x,
                                                   float* __restrict__ mu, float* __restrict__ rsig,
                                                   ushort* __restrict__ xf){
  int pos = blockIdx.x*256 + threadIdx.x;
  int b = pos >> 14, l = pos & (L-1);
  const float* xp = x + (size_t)b*C0*L + l;
  ushort* base = xf + (size_t)b*C0*L;
  int pt = l >> 4, c16 = l & 15;
  float s=0.f, ss=0.f;
  #pragma unroll
  for (int st=0; st<6; ++st)
    #pragma unroll
    for (int g=0; g<4; ++g){
      ushort u8[8];
      #pragma unroll
      for (int j=0;j<8;++j){
        float v = xp[(size_t)(st*32 + g*8 + j)*L];
        s += v; ss += v*v; u8[j] = f2u(v);
      }
      *(uint4*)(base + ((size_t)(pt*6+st)*64 + g*16 + c16)*8) = *(const uint4*)u8;
    }
  float m = s*(1.f/C0);
  float var = ss*(1.f/C0) - m*m;
  mu[pos]=m; rsig[pos]=rsqrtf(var + 1e-5f);
}

__global__ void finln_k(const float* __restrict__ sum, const float* __restrict__ ss,
                        float* __restrict__ mu, float* __restrict__ rs){
  int i = blockIdx.x*256 + threadIdx.x;
  float m = sum[i]*(1.f/C0);
  float v = ss[i]*(1.f/C0) - m*m;
  mu[i] = m; rs[i] = rsqrtf(v + 1e-5f);
}

// ---------------- weight packing: MFMA-fragment order ----------------
__global__ void packwf_k(const float* __restrict__ W, const float* __restrict__ lnw,
                         ushort* __restrict__ out, int Csrc, int O, int KS, int total){
  int idx = blockIdx.x*256 + threadIdx.x;
  if (idx >= total) return;
  int j = idx & 7; int t = idx >> 3;
  int lane = t & 63; t >>= 6;
  int st = t % KS; int mt = t / KS;
  int m = mt*16 + (lane & 15);
  int k = st*32 + (lane >> 4)*8 + j;
  float v = 0.f;
  if (m < O && k < Csrc){ v = W[(size_t)m*Csrc + k]; if (lnw) v *= lnw[k]; }
  out[idx] = f2u(v);
}

__global__ void prepab_k(const float* __restrict__ W, const float* __restrict__ lnw,
                         const float* __restrict__ lnb, float* __restrict__ A, float* __restrict__ Bv,
                         int Cc, int O, int Opad){
  int o = blockIdx.x*256 + threadIdx.x;
  if (o >= Opad) return;
  float a=0.f,b=0.f;
  if (o < O){
    const float* wr = W + (size_t)o*Cc;
    for (int c=0;c<Cc;++c){ float w=wr[c]; a = fmaf(w, lnw[c], a); b = fmaf(w, lnb[c], b); }
  }
  A[o]=a; Bv[o]=b;
}

// ---------------- gemm5: barrier-free streaming MFMA GEMM ----------------
// WR=2: 128xBN tile (4 waves 2x2). WR=1: 64xBN tile (4 waves, BN/4 cols each).
// EPI 0: LN bf16 out (two-pass 64-row LDS bounce); EPI 2: f32 out+=acc;
// EPI 3: f32 out=res+acc AND bf16 frag-packed outf AND per-position sum/ss atomics (WR=1,BN=128)
// min-waves: WR==2 needs ~140 VGPR (acc64+ops64+temps) -> 3; WR==1 ~80-95 -> 4 (no spill).
template<int EPI, int WR, int KS, int BN>
__global__ __launch_bounds__(256, WR==2?3:4) void gemm5_k(
    const ushort* __restrict__ Af, int aBS,
    const ushort* __restrict__ Xf, size_t xBS,
    const float* __restrict__ mu, const float* __restrict__ rs,
    const float* __restrict__ Avec, const float* __restrict__ Bvec,
    const float* __restrict__ res,
    void* __restrict__ outp, int Orows, int Ovalid,
    ushort* __restrict__ outf, float* __restrict__ sum_acc, float* __restrict__ ss_acc)
{
  constexpr int BM  = WR*64;
  constexpr int NF  = (WR==2) ? 4 : (BN/64);
  constexpr int PB  = L/BN;
  constexpr int BLD = BN+8;
  constexpr int NSH = (EPI==0)? 64*BLD : (EPI==3 ? BN*72 : 64);
  __shared__ ushort bb[NSH];

  const int tid=threadIdx.x, lane=tid&63, w=tid>>6;
  const int g16=lane>>4, c16=lane&15;
  const int cpx = gridDim.x>>3;
  const int p = (blockIdx.x&7)*cpx + (blockIdx.x>>3);   // XCD-bijective
  const int b = p / PB;
  const int l0 = (p - b*PB)*BN;
  const int mbase = blockIdx.y*BM;
  const int wr = (WR==2)? (w>>1)*64 : 0;
  const int wc = (WR==2)? (w&1)*64 : w*(BN/4);
  const int mt0 = (mbase+wr)>>4;
  const int pt0 = (l0+wc)>>4;

  const ushort* Ap = Af + (size_t)b*aBS + ((size_t)(mt0*KS)*64 + lane)*8;
  const ushort* Bp = Xf + (size_t)b*xBS + ((size_t)(pt0*KS)*64 + lane)*8;

  f32x4 acc[4][NF];
  #pragma unroll
  for (int mi=0;mi<4;++mi)
    #pragma unroll
    for (int ni=0;ni<NF;++ni){ f32x4 z={0.f,0.f,0.f,0.f}; acc[mi][ni]=z; }

  bf16x8 ar[2][4], br[2][NF];
  #pragma unroll
  for (int i=0;i<4;++i) ar[0][i] = ld_bf8(Ap + (size_t)(i*KS)*512);
  #pragma unroll
  for (int i=0;i<NF;++i) br[0][i] = ld_bf8(Bp + (size_t)(i*KS)*512);
  #pragma unroll
  for (int st=0; st<KS; ++st){
    const int cur = st&1, nxt = cur^1;
    if (st+1 < KS){
      #pragma unroll
      for (int i=0;i<4;++i)  ar[nxt][i] = ld_bf8(Ap + (size_t)(i*KS + st+1)*512);
      #pragma unroll
      for (int i=0;i<NF;++i) br[nxt][i] = ld_bf8(Bp + (size_t)(i*KS + st+1)*512);
    }
    #pragma unroll
    for (int mi=0;mi<4;++mi)
      #pragma unroll
      for (int ni=0;ni<NF;++ni)
        acc[mi][ni] = mfma16(ar[cur][mi], br[cur][ni], acc[mi][ni]);
  }

  if (EPI==0){
    constexpr int SEG = BN/64;
    #pragma unroll
    for (int half=0; half<WR; ++half){
      if (half) __syncthreads();
      if (WR==1 || wr == half*64){
        #pragma unroll
        for (int ni=0;ni<NF;++ni){
          int nl = wc + ni*16 + c16;
          int posl = b*L + l0 + nl;
          float muv = mu[posl], rsv = rs[posl];
          #pragma unroll
          for (int mi=0;mi<4;++mi)
            #pragma unroll
            for (int r=0;r<4;++r){
              int rl = mi*16 + g16*4 + r;          // local row 0..63
              int o  = mbase + wr + rl;
              bb[rl*BLD + nl] = f2u(rsv*(acc[mi][ni][r] - muv*Avec[o]) + Bvec[o]);
            }
        }
      }
      __syncthreads();
      if (tid < 64*SEG){
        int row = tid/SEG, seg = tid%SEG;
        int orow = mbase + half*64 + row;
        if (orow < Ovalid){
          ushort* dst = (ushort*)outp + ((size_t)b*Orows + orow)*L + l0 + seg*64;
          const ushort* src = &bb[row*BLD + seg*64];
          #pragma unroll
          for (int i=0;i<8;++i) *(uint4*)(dst + i*8) = *(const uint4*)(src + i*8);
        }
      }
    }
  } else if (EPI==3){
    #pragma unroll
    for (int ni=0;ni<NF;++ni){
      int nl = wc + ni*16 + c16;
      int posl = b*L + l0 + nl;
      size_t cbase = ((size_t)b*Orows + mbase)*L + l0 + nl;
      float s1=0.f, s2=0.f;
      #pragma unroll
      for (int mi=0;mi<4;++mi)
        #pragma unroll
        for (int r=0;r<4;++r){
          int ro = mi*16 + g16*4 + r;
          size_t idx = cbase + (size_t)ro*L;
          float v = res[idx] + acc[mi][ni][r];
          ((float*)outp)[idx] = v;
          s1 += v; s2 += v*v;
          bb[nl*72 + ro] = f2u(v);
        }
      s1 += __shfl_xor(s1,16,64); s1 += __shfl_xor(s1,32,64);
      s2 += __shfl_xor(s2,16,64); s2 += __shfl_xor(s2,32,64);
      if (g16==0){ atomicAdd(&sum_acc[posl], s1); atomicAdd(&ss_acc[posl], s2); }
    }
    __syncthreads();
    constexpr int PTS = BN/16;
    int ph  = tid >> 7;
    int rm  = tid & 127;
    int stl = rm >> 6;
    int gf  = (rm >> 4) & 3;
    int cf  = rm & 15;
    int stg = (mbase >> 5) + stl;
    #pragma unroll
    for (int pp=0; pp<PTS/2; ++pp){
      int ptl = ph*(PTS/2) + pp;
      int nl  = ptl*16 + cf;
      uint4 v = *(const uint4*)&bb[nl*72 + stl*32 + gf*8];
      int ptg = (l0 >> 4) + ptl;
      *(uint4*)(outf + (size_t)b*C0*L + ((size_t)(ptg*6 + stg)*64 + gf*16 + cf)*8) = v;
    }
  } else {
    #pragma unroll
    for (int ni=0;ni<NF;++ni){
      int nl = wc + ni*16 + c16;
      #pragma unroll
      for (int mi=0;mi<4;++mi)
        #pragma unroll
        for (int r=0;r<4;++r){
          int o = mbase + wr + mi*16 + g16*4 + r;
          size_t idx = ((size_t)b*Orows + o)*L + l0 + nl;
          ((float*)outp)[idx] += acc[mi][ni][r];
        }
    }
  }
}

// ---------------- depthwise 3x3, 8 px/thread, row-major out, sum-of-squares ----------------
__global__ __launch_bounds__(256) void dwconv8_k(const ushort* __restrict__ in, const float* __restrict__ w9,
    ushort* __restrict__ out, float* __restrict__ ss, int Cc, size_t inBS, size_t outBS){
  int e  = blockIdx.x*256 + threadIdx.x;
  int bc = e >> 11;
  int p  = (e & 2047) * 8;
  int c  = bc % Cc, b = bc / Cc;
  int y  = p >> 7, x0 = p & 127;
  const ushort* ip = in + (size_t)b*inBS + (size_t)c*L;
  float w[9];
  #pragma unroll
  for (int i=0;i<9;++i) w[i] = w9[c*9+i];
  float v[3][10];
  #pragma unroll
  for (int r=0;r<3;++r){
    int yy = y + r - 1;
    if ((unsigned)yy >= IMG){
      #pragma unroll
      for (int j=0;j<10;++j) v[r][j]=0.f;
    } else {
      const ushort* rp = ip + yy*IMG + x0;
      uint4 cv = *(const uint4*)rp; const ushort* us = (const ushort*)&cv;
      #pragma unroll
      for (int j=0;j<8;++j) v[r][j+1] = u2f(us[j]);
      v[r][0] = (x0>0)   ? u2f(rp[-1]) : 0.f;
      v[r][9] = (x0<120) ? u2f(rp[8])  : 0.f;
    }
  }
  float sq = 0.f; ushort o8[8];
  #pragma unroll
  for (int j=0;j<8;++j){
    float a = 0.f;
    #pragma unroll
    for (int r=0;r<3;++r)
      #pragma unroll
      for (int dx=0;dx<3;++dx) a = fmaf(w[r*3+dx], v[r][j+dx], a);
    o8[j] = f2u(a); sq += a*a;
  }
  *(uint4*)(out + (size_t)b*outBS + (size_t)c*L + p) = *(const uint4*)o8;
  #pragma unroll
  for (int off=32; off>0; off>>=1) sq += __shfl_xor(sq, off, 64);
  __shared__ float red[4];
  int wid = threadIdx.x >> 6;
  if ((threadIdx.x & 63)==0) red[wid]=sq;
  __syncthreads();
  if (threadIdx.x==0) atomicAdd(&ss[b*Cc + c], red[0]+red[1]+red[2]+red[3]);
}

// ---------------- depthwise 3x3 for v-rows, frag-packed out, XCD-swizzled, XOR-LDS ----------------
__global__ __launch_bounds__(256) void dwconvV_k(const ushort* __restrict__ in, const float* __restrict__ w9,
                                                 ushort* __restrict__ vf){
  __shared__ ushort lt[64][40];
  int xs = blockIdx.x;
  int chunk = ((xs & 7) << 5) | (xs >> 3);        // XCD-contiguous y-slices
  int st = blockIdx.y, b = blockIdx.z;
  int t = threadIdx.x;
  int c = t >> 3, xo = (t & 7)*8;
  int l0 = chunk*64;
  int y = l0 >> 7, px = (l0 & 127) + xo;
  int gc = st*32 + c;
  const ushort* ip = in + ((size_t)b*384 + C0 + gc)*L;
  const float* wp = w9 + (size_t)(C0+gc)*9;
  float w[9];
  #pragma unroll
  for (int i=0;i<9;++i) w[i] = wp[i];
  float v[3][10];
  #pragma unroll
  for (int r=0;r<3;++r){
    int yy = y + r - 1;
    if ((unsigned)yy >= IMG){
      #pragma unroll
      for (int j=0;j<10;++j) v[r][j]=0.f;
    } else {
      const ushort* rp = ip + yy*IMG + px;
      uint4 cv = *(const uint4*)rp; const ushort* us = (const ushort*)&cv;
      #pragma unroll
      for (int j=0;j<8;++j) v[r][j+1] = u2f(us[j]);
      v[r][0] = (px>0)   ? u2f(rp[-1]) : 0.f;
      v[r][9] = (px<120) ? u2f(rp[8])  : 0.f;
    }
  }
  #pragma unroll
  for (int j=0;j<8;++j){
    float a = 0.f;
    #pragma unroll
    for (int r=0;r<3;++r)
      #pragma unroll
      for (int dx=0;dx<3;++dx) a = fmaf(w[r*3+dx], v[r][j+dx], a);
    int row = xo + j;
    lt[row][c ^ (((row>>3)&3)<<3)] = f2u(a);
  }
  __syncthreads();
  int ptl = t>>6, gf = (t>>4)&3, cf = t&15;
  int rrow = ptl*16 + cf;
  int oct = gf ^ ((rrow>>3)&3);
  uint4 vv = *(const uint4*)&lt[rrow][oct*8];
  int pt = (l0>>4) + ptl;
  *(uint4*)(vf + (size_t)b*C0*L + ((size_t)(pt*6 + st)*64 + gf*16 + cf)*8) = vv;
}

// ---------------- QK^T via MFMA, k-split over L ----------------
__global__ __launch_bounds__(64) void qk_mfma_k(const ushort* __restrict__ qb, const ushort* __restrict__ kb,
                                                float* __restrict__ P){
  int ks = blockIdx.x, bh = blockIdx.y;
  int b = bh >> 2, h = bh & 3;
  int lane = threadIdx.x, g16 = lane>>4, c16 = lane&15;
  const ushort* qbase = qb + ((size_t)b*C0 + h*CHN)*L;
  const ushort* kbse  = kb + ((size_t)b*C0 + h*CHN)*L;
  f32x4 acc[3][3];
  #pragma unroll
  for (int i=0;i<3;++i)
    #pragma unroll
    for (int j=0;j<3;++j){ f32x4 z={0.f,0.f,0.f,0.f}; acc[i][j]=z; }
  int k0 = ks * (L/KSPLIT);
  for (int kk=0; kk<(L/KSPLIT)/32; ++kk){
    int kb2 = k0 + kk*32;
    bf16x8 af[3], bv[3];
    #pragma unroll
    for (int i=0;i<3;++i){
      af[i] = ld_bf8(qbase + (size_t)(i*16+c16)*L + kb2 + g16*8);
      bv[i] = ld_bf8(kbse  + (size_t)(i*16+c16)*L + kb2 + g16*8);
    }
    #pragma unroll
    for (int mi=0;mi<3;++mi)
      #pragma unroll
      for (int ni=0;ni<3;++ni)
        acc[mi][ni] = mfma16(af[mi], bv[ni], acc[mi][ni]);
  }
  float* Pp = P + ((size_t)ks*(BATCH*NH) + bh)*CHN*CHN;
  #pragma unroll
  for (int mi=0;mi<3;++mi)
    #pragma unroll
    for (int ni=0;ni<3;++ni)
      #pragma unroll
      for (int r=0;r<4;++r){
        int m = mi*16 + g16*4 + r, n = ni*16 + c16;
        Pp[m*CHN + n] = acc[mi][ni][r];
      }
}

__global__ void reduceS_k(const float* __restrict__ P, float* __restrict__ S){
  int i = blockIdx.x*256 + threadIdx.x;
  if (i >= BATCH*NH*CHN*CHN) return;
  float s = 0.f;
  for (int ks=0; ks<KSPLIT; ++ks) s += P[(size_t)ks*(BATCH*NH*CHN*CHN) + i];
  S[i] = s;
}

// ---------------- softmax + gating + Wca modulation ----------------
__global__ __launch_bounds__(64) void gating_k(const float* __restrict__ S, const float* __restrict__ qss,
                         const float* __restrict__ kss, const float* __restrict__ temp,
                         const float* __restrict__ Wca, float* __restrict__ attnF){
  int blk = blockIdx.x;
  int c  = blk % CHN; int bh = blk / CHN;
  int h  = bh & 3, b = bh >> 2;
  int d  = threadIdx.x;
  bool act = (d < CHN);

  float T  = temp[h];
  float nq = sqrtf(qss[b*C0 + h*CHN + c]);
  float rq = 1.f/fmaxf(nq, 1e-12f);
  float rk = 0.f, sv = 0.f;
  if (act){
    float nk = sqrtf(kss[b*C0 + h*CHN + d]);
    rk = 1.f/fmaxf(nk, 1e-12f);
    sv = S[((size_t)bh*CHN + c)*CHN + d];
  }
  float raw = act ? sv*rq*rk*T : -1e30f;

  float mx = raw;
  #pragma unroll
  for (int off=32; off>0; off>>=1) mx = fmaxf(mx, __shfl_xor(mx, off, 64));
  float e = act ? expf(raw - mx) : 0.f;
  float sum = e;
  #pragma unroll
  for (int off=32; off>0; off>>=1) sum += __shfl_xor(sum, off, 64);
  float a0 = e / sum;

  float r = fmaxf(raw, 0.f); r = r*r;
  float a1 = gelu_exact(r)*r;
  __shared__ float a1s[CHN];
  if (act) a1s[d] = a1;
  __syncthreads();

  if (!act) return;
  float s1 = 0.f, s2 = 0.f;
  const float* w1 = Wca + (size_t)d*CHN;
  const float* w2 = Wca + (size_t)(d+CHN)*CHN;
  #pragma unroll
  for (int j=0;j<CHN;++j){
    float aj = a1s[j];
    s1 = fmaf(w1[j], aj, s1);
    s2 = fmaf(w2[j], aj, s2);
  }
  attnF[((size_t)bh*CHN + c)*CHN + d] = a0*(1.f+s1) + s2;
}

// Mtf frag-packed
__global__ void mtf_k(const float* __restrict__ Wproj, const float* __restrict__ attnF,
                      ushort* __restrict__ Mtf){
  int idx = blockIdx.x*256 + threadIdx.x;
  if (idx >= BATCH*192*192) return;
  int j = idx & 7; int t = idx >> 3;
  int lane = t & 63; t >>= 6;
  int st = t % 6; t /= 6;
  int mt = t % 12; int b = t / 12;
  int o = mt*16 + (lane & 15);
  int d = st*32 + (lane >> 4)*8 + j;
  int h = d / CHN, dd = d % CHN;
  float s=0.f;
  for (int c=0;c<CHN;++c)
    s = fmaf(Wproj[(size_t)o*C0 + h*CHN + c],
             attnF[(((size_t)(b*NH+h))*CHN + c)*CHN + dd], s);
  Mtf[idx] = f2u(s);
}

// ---------------- GDFN dwconv + gelu gate -> frag-packed Gf, XCD-swizzled, XOR-LDS ----------------
__global__ __launch_bounds__(256) void ffn8f_k(const ushort* __restrict__ hidden, const float* __restrict__ w9,
                                               ushort* __restrict__ gf){
  __shared__ ushort lt[64][40];
  int xs = blockIdx.x;
  int chunk = ((xs & 7) << 5) | (xs >> 3);        // XCD-contiguous y-slices
  int st = blockIdx.y, b = blockIdx.z;
  int t = threadIdx.x;
  int c = t >> 3, xo = (t & 7)*8;
  int l0 = chunk*64;
  int y = l0 >> 7, px = (l0 & 127) + xo;
  int gc = st*32 + c;
  ushort o8[8];
  if (gc < HID){
    const ushort* i1 = hidden + ((size_t)b*HID2 + gc)*L;
    const ushort* i2 = i1 + (size_t)HID*L;
    float w1[9], w2[9];
    #pragma unroll
    for (int i=0;i<9;++i){ w1[i] = w9[gc*9+i]; w2[i] = w9[(HID+gc)*9+i]; }
    float v1[3][10], v2[3][10];
    #pragma unroll
    for (int r=0;r<3;++r){
      int yy = y + r - 1;
      if ((unsigned)yy >= IMG){
        #pragma unroll
        for (int j=0;j<10;++j){ v1[r][j]=0.f; v2[r][j]=0.f; }
      } else {
        const ushort* rp1 = i1 + yy*IMG + px;
        const ushort* rp2 = i2 + yy*IMG + px;
        uint4 c1 = *(const uint4*)rp1; const ushort* u1 = (const ushort*)&c1;
        uint4 c2 = *(const uint4*)rp2; const ushort* u2 = (const ushort*)&c2;
        #pragma unroll
        for (int j=0;j<8;++j){ v1[r][j+1] = u2f(u1[j]); v2[r][j+1] = u2f(u2[j]); }
        v1[r][0] = (px>0)   ? u2f(rp1[-1]) : 0.f;
        v1[r][9] = (px<120) ? u2f(rp1[8])  : 0.f;
        v2[r][0] = (px>0)   ? u2f(rp2[-1]) : 0.f;
        v2[r][9] = (px<120) ? u2f(rp2[8])  : 0.f;
      }
    }
    #pragma unroll
    for (int j=0;j<8;++j){
      float d1=0.f, d2=0.f;
      #pragma unroll
      for (int r=0;r<3;++r)
        #pragma unroll
        for (int dx=0;dx<3;++dx){
          d1 = fmaf(w1[r*3+dx], v1[r][j+dx], d1);
          d2 = fmaf(w2[r*3+dx], v2[r][j+dx], d2);
        }
      o8[j] = f2u(gelu_exact(d1)*d2);
    }
  } else {
    #pragma unroll
    for (int j=0;j<8;++j) o8[j] = 0;
  }
  #pragma unroll
  for (int j=0;j<8;++j){
    int row = xo + j;
    lt[row][c ^ (((row>>3)&3)<<3)] = o8[j];
  }
  __syncthreads();
  int ptl = t>>6, gfr = (t>>4)&3, cf = t&15;
  int rrow = ptl*16 + cf;
  int oct = gfr ^ ((rrow>>3)&3);
  uint4 vv = *(const uint4*)&lt[rrow][oct*8];
  int pt = (l0>>4) + ptl;
  *(uint4*)(gf + (size_t)b*512*L + ((size_t)(pt*16 + st)*64 + gfr*16 + cf)*8) = vv;
}

extern "C" void kernel_launch(void* const* d_in, const int* in_sizes, int n_in,
                              void* d_out, int out_size, void* d_ws, size_t ws_size,
                              hipStream_t stream){
  (void)in_sizes; (void)n_in; (void)out_size; (void)ws_size;
  const float* lr    = (const float*)d_in[0];
  const float* ref   = (const float*)d_in[1];
  const float* ln1w  = (const float*)d_in[2];
  const float* ln1b  = (const float*)d_in[3];
  const float* lnrw  = (const float*)d_in[4];
  const float* lnrb  = (const float*)d_in[5];
  const float* ln2w  = (const float*)d_in[6];
  const float* ln2b  = (const float*)d_in[7];
  const float* Wq    = (const float*)d_in[8];
  const float* qdw   = (const float*)d_in[9];
  const float* Wkv   = (const float*)d_in[10];
  const float* kvdw  = (const float*)d_in[11];
  const float* Wproj = (const float*)d_in[12];
  const float* Wca   = (const float*)d_in[13];
  const float* temp  = (const float*)d_in[14];
  const float* Wpin  = (const float*)d_in[15];
  const float* ffndw = (const float*)d_in[16];
  const float* Wpout = (const float*)d_in[17];
  float* out = (float*)d_out;

  char* ws = (char*)d_ws;
  size_t off = 0;
  auto alloc = [&](size_t bytes)->void*{ void* p = ws + off; off += (bytes + 255) & ~(size_t)255; return p; };

  ushort* Aqf    = (ushort*)alloc((size_t)192*192*2);
  ushort* Akvf   = (ushort*)alloc((size_t)384*192*2);
  ushort* Apinf  = (ushort*)alloc((size_t)1024*192*2);
  ushort* Apoutf = (ushort*)alloc((size_t)192*512*2);
  ushort* Mtf    = (ushort*)alloc((size_t)BATCH*192*192*2);
  float* Aqv  = (float*)alloc(192*4);   float* Bqv  = (float*)alloc(192*4);
  float* Akvv = (float*)alloc(384*4);   float* Bkvv = (float*)alloc(384*4);
  float* Apinv= (float*)alloc(1024*4);  float* Bpinv= (float*)alloc(1024*4);
  float* mu_lr = (float*)alloc((size_t)BL*4);  float* rs_lr = (float*)alloc((size_t)BL*4);
  float* mu_rf = (float*)alloc((size_t)BL*4);  float* rs_rf = (float*)alloc((size_t)BL*4);
  float* mu_o  = (float*)alloc((size_t)BL*4);  float* rs_o  = (float*)alloc((size_t)BL*4);
  float* sum_o = (float*)alloc((size_t)BL*4);  float* ssq_o = (float*)alloc((size_t)BL*4);
  float* qss   = (float*)alloc((size_t)BATCH*C0*4);
  float* kss   = (float*)alloc((size_t)BATCH*C0*4);
  float* S     = (float*)alloc((size_t)BATCH*NH*CHN*CHN*4);
  float* attnF = (float*)alloc((size_t)BATCH*NH*CHN*CHN*4);
  char*  pool  = (char*)alloc((size_t)104857600);

  // region map (sequential reuse):
  ushort* LRf    = (ushort*)(pool);                    // [0, 12.6M)
  ushort* REFf   = (ushort*)(pool + 12582912);         // [12.6, 25.2)
  ushort* q_pre  = (ushort*)(pool + 25165824);         // [25.2, 37.8)
  ushort* kv_pre = (ushort*)(pool + 37748736);         // [37.8, 63.0)
  ushort* qb     = (ushort*)(pool + 62914560);         // [63.0, 75.6)
  ushort* kvb_k  = (ushort*)(pool + 75497472);         // [75.6, 88.1)  k-rows only
  ushort* Vf     = (ushort*)(pool + 88080384);         // [88.1, 100.7) frag-packed v
  float*  Pp     = (float*) (pool);                    // 18.9M over LRf+REFf
  ushort* OUTf   = (ushort*)(pool);                    // 12.6M over Pp
  ushort* hidden = (ushort*)(pool + 33554432);         // 66.8M over kv_pre..Vf
  ushort* Gf     = (ushort*)(pool);                    // 33.5M over OUTf+REFf+q_pre

  hipMemsetAsync(qss, 0, (size_t)BATCH*C0*4, stream);
  hipMemsetAsync(kss, 0, (size_t)BATCH*C0*4, stream);
  hipMemsetAsync(sum_o, 0, (size_t)BL*4, stream);
  hipMemsetAsync(ssq_o, 0, (size_t)BL*4, stream);

  // weight prep (frag-packed)
  packwf_k<<<144,256,0,stream>>>(Wq,   ln1w, Aqf,   192, 192, 6, 192*192);
  packwf_k<<<288,256,0,stream>>>(Wkv,  lnrw, Akvf,  192, 384, 6, 384*192);
  packwf_k<<<768,256,0,stream>>>(Wpin, ln2w, Apinf, 192, 1020, 6, 1024*192);
  packwf_k<<<384,256,0,stream>>>(Wpout, nullptr, Apoutf, 510, 192, 16, 192*512);
  prepab_k<<<1,256,0,stream>>>(Wq,  ln1w, ln1b, Aqv,  Bqv,  192, 192, 192);
  prepab_k<<<2,256,0,stream>>>(Wkv, lnrw, lnrb, Akvv, Bkvv, 192, 384, 384);
  prepab_k<<<4,256,0,stream>>>(Wpin,ln2w, ln2b, Apinv,Bpinv,192, 1020, 1024);

  // LN stats + frag-packed mirrors
  ln_stats3_k<<<BL/256,256,0,stream>>>(lr,  mu_lr, rs_lr, LRf);
  ln_stats3_k<<<BL/256,256,0,stream>>>(ref, mu_rf, rs_rf, REFf);

  // fused LN + 1x1 conv GEMMs
  gemm5_k<0,1,6,128><<<dim3(256,3),256,0,stream>>>(Aqf, 0, LRf, (size_t)C0*L,
      mu_lr, rs_lr, Aqv, Bqv, nullptr, q_pre, 192, 192, nullptr, nullptr, nullptr);
  gemm5_k<0,2,6,128><<<dim3(256,3),256,0,stream>>>(Akvf, 0, REFf, (size_t)C0*L,
      mu_rf, rs_rf, Akvv, Bkvv, nullptr, kv_pre, 384, 384, nullptr, nullptr, nullptr);

  // depthwise convs: q and k row-major (+ss), v direct frag-packed
  dwconv8_k<<<3072,256,0,stream>>>(q_pre,  qdw,  qb,    qss, 192, (size_t)192*L, (size_t)192*L);
  dwconv8_k<<<3072,256,0,stream>>>(kv_pre, kvdw, kvb_k, kss, 192, (size_t)384*L, (size_t)192*L);
  dwconvV_k<<<dim3(256,6,2),256,0,stream>>>(kv_pre, kvdw, Vf);

  // attention core
  qk_mfma_k<<<dim3(KSPLIT, BATCH*NH),64,0,stream>>>(qb, kvb_k, Pp);
  reduceS_k<<<(BATCH*NH*CHN*CHN+255)/256,256,0,stream>>>(Pp, S);
  gating_k<<<BATCH*NH*CHN,64,0,stream>>>(S, qss, kss, temp, Wca, attnF);
  mtf_k<<<288,256,0,stream>>>(Wproj, attnF, Mtf);

  // out = lr + Mt.v  (+ frag-packed OUTf + LN-stat atomics fused)
  gemm5_k<3,1,6,128><<<dim3(256,3),256,0,stream>>>(Mtf, 192*192, Vf, (size_t)C0*L,
      nullptr, nullptr, nullptr, nullptr, lr, out, 192, 192, OUTf, sum_o, ssq_o);
  finln_k<<<BL/256,256,0,stream>>>(sum_o, ssq_o, mu_o, rs_o);

  // GDFN
  gemm5_k<0,2,6,128><<<dim3(256,8),256,0,stream>>>(Apinf, 0, OUTf, (size_t)C0*L,
      mu_o, rs_o, Apinv, Bpinv, nullptr, hidden, 1020, 1020, nullptr, nullptr, nullptr);
  ffn8f_k<<<dim3(256,16,2),256,0,stream>>>(hidden, ffndw, Gf);
  gemm5_k<2,1,16,128><<<dim3(256,3),256,0,stream>>>(Apoutf, 0, Gf, (size_t)512*L,
      nullptr, nullptr, nullptr, nullptr, nullptr, out, 192, 192, nullptr, nullptr, nullptr);
}

// Round 13
// 264.554 us; speedup vs baseline: 1.5212x; 1.3610x over previous
//
#include <hip/hip_runtime.h>
#include <hip/hip_bf16.h>
#include <math.h>

#define L     16384
#define IMG   128
#define BATCH 2
#define C0    192
#define NH    4
#define CHN   48
#define HID   510
#define HID2  1020
#define BL    (BATCH*L)
#define KSPL  128

typedef float  f32x4  __attribute__((ext_vector_type(4)));
typedef __bf16 bf16x8 __attribute__((ext_vector_type(8)));

union UB16 { uint4 u; bf16x8 v; };

__device__ __forceinline__ bf16x8 ld_bf8(const ushort* p){ UB16 x; x.u = *(const uint4*)p; return x.v; }
__device__ __forceinline__ f32x4 mfma16(bf16x8 a, bf16x8 b, f32x4 c){
  return __builtin_amdgcn_mfma_f32_16x16x32_bf16(a, b, c, 0, 0, 0);
}
__device__ __forceinline__ float u2f(ushort u){ union{unsigned u; float f;} x; x.u = ((unsigned)u)<<16; return x.f; }
__device__ __forceinline__ ushort f2u(float f){ __hip_bfloat16 h = __float2bfloat16(f); return *reinterpret_cast<ushort*>(&h); }
__device__ __forceinline__ float gelu_exact(float x){ return 0.5f*x*(1.0f+erff(x*0.70710678118654752f)); }

// ---------------- LN stats + frag-packed bf16 mirror, two tensors in one launch ----------------
__global__ __launch_bounds__(256) void ln_stats3_k(const float* __restrict__ x0, const float* __restrict__ x1,
                                                   float* __restrict__ mu0, float* __restrict__ rs0,
                                                   float* __restrict__ mu1, float* __restrict__ rs1,
                                                   ushort* __restrict__ xf0, ushort* __restrict__ xf1){
  int z = blockIdx.y;
  const float* x = z ? x1 : x0;
  float* mu = z ? mu1 : mu0;
  float* rsig = z ? rs1 : rs0;
  ushort* xf = z ? xf1 : xf0;
  int pos = blockIdx.x*256 + threadIdx.x;
  int b = pos >> 14, l = pos & (L-1);
  const float* xp = x + (size_t)b*C0*L + l;
  ushort* base = xf + (size_t)b*C0*L;
  int pt = l >> 4, c16 = l & 15;
  float s=0.f, ss=0.f;
  #pragma unroll
  for (int st=0; st<6; ++st)
    #pragma unroll
    for (int g=0; g<4; ++g){
      ushort u8[8];
      #pragma unroll
      for (int j=0;j<8;++j){
        float v = xp[(size_t)(st*32 + g*8 + j)*L];
        s += v; ss += v*v; u8[j] = f2u(v);
      }
      *(uint4*)(base + ((size_t)(pt*6+st)*64 + g*16 + c16)*8) = *(const uint4*)u8;
    }
  float m = s*(1.f/C0);
  float var = ss*(1.f/C0) - m*m;
  mu[pos]=m; rsig[pos]=rsqrtf(var + 1e-5f);
}

__global__ void finln_k(const float* __restrict__ sum, const float* __restrict__ ss,
                        float* __restrict__ mu, float* __restrict__ rs){
  int i = blockIdx.x*256 + threadIdx.x;
  float m = sum[i]*(1.f/C0);
  float v = ss[i]*(1.f/C0) - m*m;
  mu[i] = m; rs[i] = rsqrtf(v + 1e-5f);
}

// ---------------- unified weight-prep kernel ----------------
__device__ __forceinline__ void packwf_body(const float* __restrict__ W, const float* __restrict__ lnw,
                                            ushort* __restrict__ out, int Csrc, int O, int KS,
                                            int idx, int total){
  if (idx >= total) return;
  int j = idx & 7; int t = idx >> 3;
  int lane = t & 63; t >>= 6;
  int st = t % KS; int mt = t / KS;
  int m = mt*16 + (lane & 15);
  int k = st*32 + (lane >> 4)*8 + j;
  float v = 0.f;
  if (m < O && k < Csrc){ v = W[(size_t)m*Csrc + k]; if (lnw) v *= lnw[k]; }
  out[idx] = f2u(v);
}
__device__ __forceinline__ void prepab_body(const float* __restrict__ W, const float* __restrict__ lnw,
                                            const float* __restrict__ lnb, float* __restrict__ A,
                                            float* __restrict__ Bv, int Cc, int O, int Opad, int o){
  if (o >= Opad) return;
  float a=0.f,b=0.f;
  if (o < O){
    const float* wr = W + (size_t)o*Cc;
    for (int c=0;c<Cc;++c){ float w=wr[c]; a = fmaf(w, lnw[c], a); b = fmaf(w, lnb[c], b); }
  }
  A[o]=a; Bv[o]=b;
}

__global__ void prep_all_k(const float* Wq, const float* ln1w, const float* ln1b, ushort* Aqf, float* Aqv, float* Bqv,
                           const float* Wkv, const float* lnrw, const float* lnrb, ushort* Akvf, float* Akvv, float* Bkvv,
                           const float* Wpin, const float* ln2w, const float* ln2b, ushort* Apinf, float* Apinv, float* Bpinv,
                           const float* Wpout, ushort* Apoutf){
  int bx = blockIdx.x, tid = threadIdx.x;
  if (bx < 144)        packwf_body(Wq,   ln1w, Aqf,   192, 192, 6,  bx*256+tid,        36864);
  else if (bx < 432)   packwf_body(Wkv,  lnrw, Akvf,  192, 384, 6,  (bx-144)*256+tid,  73728);
  else if (bx < 1200)  packwf_body(Wpin, ln2w, Apinf, 192, 1020, 6, (bx-432)*256+tid,  196608);
  else if (bx < 1584)  packwf_body(Wpout, nullptr, Apoutf, 510, 192, 16, (bx-1200)*256+tid, 98304);
  else if (bx == 1584) prepab_body(Wq,  ln1w, ln1b, Aqv,  Bqv,  192, 192, 192,  tid);
  else if (bx < 1587)  prepab_body(Wkv, lnrw, lnrb, Akvv, Bkvv, 192, 384, 384,  (bx-1585)*256+tid);
  else                 prepab_body(Wpin,ln2w, ln2b, Apinv,Bpinv,192, 1020, 1024,(bx-1587)*256+tid);
}

// ---------------- gemm5: barrier-free streaming MFMA GEMM ----------------
// WR=2: 128xBN tile (4 waves 2x2). WR=1: 64xBN tile (4 waves, BN/4 cols each).
// EPI 0: LN bf16 out (single-pass LDS bounce); EPI 2: f32 out+=acc;
// EPI 3: f32 out=res+acc AND bf16 frag-packed outf AND per-position sum/ss atomics (WR=1,BN=128)
template<int EPI, int WR, int KS, int BN>
__global__ __launch_bounds__(256, WR==2?3:4) void gemm5_k(
    const ushort* __restrict__ Af, int aBS,
    const ushort* __restrict__ Xf, size_t xBS,
    const float* __restrict__ mu, const float* __restrict__ rs,
    const float* __restrict__ Avec, const float* __restrict__ Bvec,
    const float* __restrict__ res,
    void* __restrict__ outp, int Orows, int Ovalid,
    ushort* __restrict__ outf, float* __restrict__ sum_acc, float* __restrict__ ss_acc)
{
  constexpr int BM  = WR*64;
  constexpr int NF  = (WR==2) ? 4 : (BN/64);
  constexpr int PB  = L/BN;
  constexpr int BLD = BN+8;
  constexpr int NSH = (EPI==0)? BM*BLD : (EPI==3 ? BN*72 : 64);
  __shared__ ushort bb[NSH];

  const int tid=threadIdx.x, lane=tid&63, w=tid>>6;
  const int g16=lane>>4, c16=lane&15;
  const int cpx = gridDim.x>>3;
  const int p = (blockIdx.x&7)*cpx + (blockIdx.x>>3);   // XCD-bijective
  const int b = p / PB;
  const int l0 = (p - b*PB)*BN;
  const int mbase = blockIdx.y*BM;
  const int wr = (WR==2)? (w>>1)*64 : 0;
  const int wc = (WR==2)? (w&1)*64 : w*(BN/4);
  const int mt0 = (mbase+wr)>>4;
  const int pt0 = (l0+wc)>>4;

  const ushort* Ap = Af + (size_t)b*aBS + ((size_t)(mt0*KS)*64 + lane)*8;
  const ushort* Bp = Xf + (size_t)b*xBS + ((size_t)(pt0*KS)*64 + lane)*8;

  f32x4 acc[4][NF];
  #pragma unroll
  for (int mi=0;mi<4;++mi)
    #pragma unroll
    for (int ni=0;ni<NF;++ni){ f32x4 z={0.f,0.f,0.f,0.f}; acc[mi][ni]=z; }

  bf16x8 ar[2][4], br[2][NF];
  #pragma unroll
  for (int i=0;i<4;++i) ar[0][i] = ld_bf8(Ap + (size_t)(i*KS)*512);
  #pragma unroll
  for (int i=0;i<NF;++i) br[0][i] = ld_bf8(Bp + (size_t)(i*KS)*512);
  #pragma unroll
  for (int st=0; st<KS; ++st){
    const int cur = st&1, nxt = cur^1;
    if (st+1 < KS){
      #pragma unroll
      for (int i=0;i<4;++i)  ar[nxt][i] = ld_bf8(Ap + (size_t)(i*KS + st+1)*512);
      #pragma unroll
      for (int i=0;i<NF;++i) br[nxt][i] = ld_bf8(Bp + (size_t)(i*KS + st+1)*512);
    }
    #pragma unroll
    for (int mi=0;mi<4;++mi)
      #pragma unroll
      for (int ni=0;ni<NF;++ni)
        acc[mi][ni] = mfma16(ar[cur][mi], br[cur][ni], acc[mi][ni]);
  }

  if (EPI==0){
    #pragma unroll
    for (int ni=0;ni<NF;++ni){
      int nl = wc + ni*16 + c16;
      int posl = b*L + l0 + nl;
      float muv = mu[posl], rsv = rs[posl];
      #pragma unroll
      for (int mi=0;mi<4;++mi)
        #pragma unroll
        for (int r=0;r<4;++r){
          int ro = wr + mi*16 + g16*4 + r;
          int o  = mbase + ro;
          bb[ro*BLD + nl] = f2u(rsv*(acc[mi][ni][r] - muv*Avec[o]) + Bvec[o]);
        }
    }
    __syncthreads();
    constexpr int SEG = BN/64;
    constexpr int JOBS = BM*SEG;
    if (tid < JOBS){
      int row = tid/SEG, seg = tid%SEG;
      if (mbase + row < Ovalid){
        ushort* dst = (ushort*)outp + ((size_t)b*Orows + mbase + row)*L + l0 + seg*64;
        const ushort* src = &bb[row*BLD + seg*64];
        #pragma unroll
        for (int i=0;i<8;++i) *(uint4*)(dst + i*8) = *(const uint4*)(src + i*8);
      }
    }
  } else if (EPI==3){
    #pragma unroll
    for (int ni=0;ni<NF;++ni){
      int nl = wc + ni*16 + c16;
      int posl = b*L + l0 + nl;
      size_t cbase = ((size_t)b*Orows + mbase)*L + l0 + nl;
      float s1=0.f, s2=0.f;
      #pragma unroll
      for (int mi=0;mi<4;++mi)
        #pragma unroll
        for (int r=0;r<4;++r){
          int ro = mi*16 + g16*4 + r;
          size_t idx = cbase + (size_t)ro*L;
          float v = res[idx] + acc[mi][ni][r];
          ((float*)outp)[idx] = v;
          s1 += v; s2 += v*v;
          bb[nl*72 + ro] = f2u(v);
        }
      s1 += __shfl_xor(s1,16,64); s1 += __shfl_xor(s1,32,64);
      s2 += __shfl_xor(s2,16,64); s2 += __shfl_xor(s2,32,64);
      if (g16==0){ atomicAdd(&sum_acc[posl], s1); atomicAdd(&ss_acc[posl], s2); }
    }
    __syncthreads();
    constexpr int PTS = BN/16;
    int ph  = tid >> 7;
    int rm  = tid & 127;
    int stl = rm >> 6;
    int gf  = (rm >> 4) & 3;
    int cf  = rm & 15;
    int stg = (mbase >> 5) + stl;
    #pragma unroll
    for (int pp=0; pp<PTS/2; ++pp){
      int ptl = ph*(PTS/2) + pp;
      int nl  = ptl*16 + cf;
      uint4 v = *(const uint4*)&bb[nl*72 + stl*32 + gf*8];
      int ptg = (l0 >> 4) + ptl;
      *(uint4*)(outf + (size_t)b*C0*L + ((size_t)(ptg*6 + stg)*64 + gf*16 + cf)*8) = v;
    }
  } else {
    #pragma unroll
    for (int ni=0;ni<NF;++ni){
      int nl = wc + ni*16 + c16;
      #pragma unroll
      for (int mi=0;mi<4;++mi)
        #pragma unroll
        for (int r=0;r<4;++r){
          int o = mbase + wr + mi*16 + g16*4 + r;
          size_t idx = ((size_t)b*Orows + o)*L + l0 + nl;
          ((float*)outp)[idx] += acc[mi][ni][r];
        }
    }
  }
}

// ---------------- depthwise 3x3 for q and k in one launch, row-major out + sum-of-squares ----------------
__global__ __launch_bounds__(256) void dwconvQK_k(const ushort* __restrict__ qpre, const ushort* __restrict__ kvpre,
    const float* __restrict__ qdw, const float* __restrict__ kvdw,
    ushort* __restrict__ qb, ushort* __restrict__ kb,
    float* __restrict__ qss, float* __restrict__ kss){
  int bx = blockIdx.x;
  bool isK = bx >= 3072;
  const ushort* in = isK ? kvpre : qpre;
  size_t inBS = isK ? (size_t)384*L : (size_t)192*L;
  const float* w9 = isK ? kvdw : qdw;
  ushort* out = isK ? kb : qb;
  float* ss = isK ? kss : qss;
  int e  = (isK ? bx-3072 : bx)*256 + threadIdx.x;
  int bc = e >> 11;
  int p  = (e & 2047) * 8;
  int c  = bc % 192, b = bc / 192;
  int y  = p >> 7, x0 = p & 127;
  const ushort* ip = in + (size_t)b*inBS + (size_t)c*L;
  float w[9];
  #pragma unroll
  for (int i=0;i<9;++i) w[i] = w9[c*9+i];
  float v[3][10];
  #pragma unroll
  for (int r=0;r<3;++r){
    int yy = y + r - 1;
    if ((unsigned)yy >= IMG){
      #pragma unroll
      for (int j=0;j<10;++j) v[r][j]=0.f;
    } else {
      const ushort* rp = ip + yy*IMG + x0;
      uint4 cv = *(const uint4*)rp; const ushort* us = (const ushort*)&cv;
      #pragma unroll
      for (int j=0;j<8;++j) v[r][j+1] = u2f(us[j]);
      v[r][0] = (x0>0)   ? u2f(rp[-1]) : 0.f;
      v[r][9] = (x0<120) ? u2f(rp[8])  : 0.f;
    }
  }
  float sq = 0.f; ushort o8[8];
  #pragma unroll
  for (int j=0;j<8;++j){
    float a = 0.f;
    #pragma unroll
    for (int r=0;r<3;++r)
      #pragma unroll
      for (int dx=0;dx<3;++dx) a = fmaf(w[r*3+dx], v[r][j+dx], a);
    o8[j] = f2u(a); sq += a*a;
  }
  *(uint4*)(out + (size_t)b*(size_t)192*L + (size_t)c*L + p) = *(const uint4*)o8;
  #pragma unroll
  for (int off=32; off>0; off>>=1) sq += __shfl_xor(sq, off, 64);
  __shared__ float red[4];
  int wid = threadIdx.x >> 6;
  if ((threadIdx.x & 63)==0) red[wid]=sq;
  __syncthreads();
  if (threadIdx.x==0) atomicAdd(&ss[b*192 + c], red[0]+red[1]+red[2]+red[3]);
}

// ---------------- depthwise 3x3 for v-rows, frag-packed out, XCD-swizzled, XOR-LDS ----------------
__global__ __launch_bounds__(256) void dwconvV_k(const ushort* __restrict__ in, const float* __restrict__ w9,
                                                 ushort* __restrict__ vf){
  __shared__ ushort lt[64][40];
  int xs = blockIdx.x;
  int chunk = ((xs & 7) << 5) | (xs >> 3);
  int st = blockIdx.y, b = blockIdx.z;
  int t = threadIdx.x;
  int c = t >> 3, xo = (t & 7)*8;
  int l0 = chunk*64;
  int y = l0 >> 7, px = (l0 & 127) + xo;
  int gc = st*32 + c;
  const ushort* ip = in + ((size_t)b*384 + C0 + gc)*L;
  const float* wp = w9 + (size_t)(C0+gc)*9;
  float w[9];
  #pragma unroll
  for (int i=0;i<9;++i) w[i] = wp[i];
  float v[3][10];
  #pragma unroll
  for (int r=0;r<3;++r){
    int yy = y + r - 1;
    if ((unsigned)yy >= IMG){
      #pragma unroll
      for (int j=0;j<10;++j) v[r][j]=0.f;
    } else {
      const ushort* rp = ip + yy*IMG + px;
      uint4 cv = *(const uint4*)rp; const ushort* us = (const ushort*)&cv;
      #pragma unroll
      for (int j=0;j<8;++j) v[r][j+1] = u2f(us[j]);
      v[r][0] = (px>0)   ? u2f(rp[-1]) : 0.f;
      v[r][9] = (px<120) ? u2f(rp[8])  : 0.f;
    }
  }
  #pragma unroll
  for (int j=0;j<8;++j){
    float a = 0.f;
    #pragma unroll
    for (int r=0;r<3;++r)
      #pragma unroll
      for (int dx=0;dx<3;++dx) a = fmaf(w[r*3+dx], v[r][j+dx], a);
    int row = xo + j;
    lt[row][c ^ (((row>>3)&3)<<3)] = f2u(a);
  }
  __syncthreads();
  int ptl = t>>6, gf = (t>>4)&3, cf = t&15;
  int rrow = ptl*16 + cf;
  int oct = gf ^ ((rrow>>3)&3);
  uint4 vv = *(const uint4*)&lt[rrow][oct*8];
  int pt = (l0>>4) + ptl;
  *(uint4*)(vf + (size_t)b*C0*L + ((size_t)(pt*6 + st)*64 + gf*16 + cf)*8) = vv;
}

// ---------------- QK^T via MFMA, k-split over L ----------------
__global__ __launch_bounds__(64) void qk_mfma_k(const ushort* __restrict__ qb, const ushort* __restrict__ kb,
                                                float* __restrict__ P){
  int ks = blockIdx.x, bh = blockIdx.y;
  int b = bh >> 2, h = bh & 3;
  int lane = threadIdx.x, g16 = lane>>4, c16 = lane&15;
  const ushort* qbase = qb + ((size_t)b*C0 + h*CHN)*L;
  const ushort* kbse  = kb + ((size_t)b*C0 + h*CHN)*L;
  f32x4 acc[3][3];
  #pragma unroll
  for (int i=0;i<3;++i)
    #pragma unroll
    for (int j=0;j<3;++j){ f32x4 z={0.f,0.f,0.f,0.f}; acc[i][j]=z; }
  int k0 = ks * (L/KSPL);
  for (int kk=0; kk<(L/KSPL)/32; ++kk){
    int kb2 = k0 + kk*32;
    bf16x8 af[3], bv[3];
    #pragma unroll
    for (int i=0;i<3;++i){
      af[i] = ld_bf8(qbase + (size_t)(i*16+c16)*L + kb2 + g16*8);
      bv[i] = ld_bf8(kbse  + (size_t)(i*16+c16)*L + kb2 + g16*8);
    }
    #pragma unroll
    for (int mi=0;mi<3;++mi)
      #pragma unroll
      for (int ni=0;ni<3;++ni)
        acc[mi][ni] = mfma16(af[mi], bv[ni], acc[mi][ni]);
  }
  float* Pp = P + ((size_t)ks*(BATCH*NH) + bh)*CHN*CHN;
  #pragma unroll
  for (int mi=0;mi<3;++mi)
    #pragma unroll
    for (int ni=0;ni<3;++ni)
      #pragma unroll
      for (int r=0;r<4;++r){
        int m = mi*16 + g16*4 + r, n = ni*16 + c16;
        Pp[m*CHN + n] = acc[mi][ni][r];
      }
}

// ---------------- Pp-reduce + softmax + gating + Wca modulation ----------------
__global__ __launch_bounds__(64) void gating_k(const float* __restrict__ Pp, const float* __restrict__ qss,
                         const float* __restrict__ kss, const float* __restrict__ temp,
                         const float* __restrict__ Wca, float* __restrict__ attnF){
  int blk = blockIdx.x;
  int c  = blk % CHN; int bh = blk / CHN;
  int h  = bh & 3, b = bh >> 2;
  int d  = threadIdx.x;
  bool act = (d < CHN);

  float sv = 0.f;
  if (act){
    const float* pr = Pp + (size_t)bh*CHN*CHN + c*CHN + d;
    for (int ks=0; ks<KSPL; ++ks) sv += pr[(size_t)ks*(BATCH*NH)*CHN*CHN];
  }

  float T  = temp[h];
  float nq = sqrtf(qss[b*C0 + h*CHN + c]);
  float rq = 1.f/fmaxf(nq, 1e-12f);
  float rk = 0.f;
  if (act){
    float nk = sqrtf(kss[b*C0 + h*CHN + d]);
    rk = 1.f/fmaxf(nk, 1e-12f);
  }
  float raw = act ? sv*rq*rk*T : -1e30f;

  float mx = raw;
  #pragma unroll
  for (int off=32; off>0; off>>=1) mx = fmaxf(mx, __shfl_xor(mx, off, 64));
  float e = act ? expf(raw - mx) : 0.f;
  float sum = e;
  #pragma unroll
  for (int off=32; off>0; off>>=1) sum += __shfl_xor(sum, off, 64);
  float a0 = e / sum;

  float r = fmaxf(raw, 0.f); r = r*r;
  float a1 = gelu_exact(r)*r;
  __shared__ float a1s[CHN];
  if (act) a1s[d] = a1;
  __syncthreads();

  if (!act) return;
  float s1 = 0.f, s2 = 0.f;
  const float* w1 = Wca + (size_t)d*CHN;
  const float* w2 = Wca + (size_t)(d+CHN)*CHN;
  #pragma unroll
  for (int j=0;j<CHN;++j){
    float aj = a1s[j];
    s1 = fmaf(w1[j], aj, s1);
    s2 = fmaf(w2[j], aj, s2);
  }
  attnF[((size_t)bh*CHN + c)*CHN + d] = a0*(1.f+s1) + s2;
}

// Mtf frag-packed
__global__ void mtf_k(const float* __restrict__ Wproj, const float* __restrict__ attnF,
                      ushort* __restrict__ Mtf){
  int idx = blockIdx.x*256 + threadIdx.x;
  if (idx >= BATCH*192*192) return;
  int j = idx & 7; int t = idx >> 3;
  int lane = t & 63; t >>= 6;
  int st = t % 6; t /= 6;
  int mt = t % 12; int b = t / 12;
  int o = mt*16 + (lane & 15);
  int d = st*32 + (lane >> 4)*8 + j;
  int h = d / CHN, dd = d % CHN;
  float s=0.f;
  for (int c=0;c<CHN;++c)
    s = fmaf(Wproj[(size_t)o*C0 + h*CHN + c],
             attnF[(((size_t)(b*NH+h))*CHN + c)*CHN + dd], s);
  Mtf[idx] = f2u(s);
}

// ---------------- GDFN dwconv + gelu gate -> frag-packed Gf, XCD-swizzled, XOR-LDS ----------------
__global__ __launch_bounds__(256) void ffn8f_k(const ushort* __restrict__ hidden, const float* __restrict__ w9,
                                               ushort* __restrict__ gf){
  __shared__ ushort lt[64][40];
  int xs = blockIdx.x;
  int chunk = ((xs & 7) << 5) | (xs >> 3);
  int st = blockIdx.y, b = blockIdx.z;
  int t = threadIdx.x;
  int c = t >> 3, xo = (t & 7)*8;
  int l0 = chunk*64;
  int y = l0 >> 7, px = (l0 & 127) + xo;
  int gc = st*32 + c;
  ushort o8[8];
  if (gc < HID){
    const ushort* i1 = hidden + ((size_t)b*HID2 + gc)*L;
    const ushort* i2 = i1 + (size_t)HID*L;
    float w1[9], w2[9];
    #pragma unroll
    for (int i=0;i<9;++i){ w1[i] = w9[gc*9+i]; w2[i] = w9[(HID+gc)*9+i]; }
    float v1[3][10], v2[3][10];
    #pragma unroll
    for (int r=0;r<3;++r){
      int yy = y + r - 1;
      if ((unsigned)yy >= IMG){
        #pragma unroll
        for (int j=0;j<10;++j){ v1[r][j]=0.f; v2[r][j]=0.f; }
      } else {
        const ushort* rp1 = i1 + yy*IMG + px;
        const ushort* rp2 = i2 + yy*IMG + px;
        uint4 c1 = *(const uint4*)rp1; const ushort* u1 = (const ushort*)&c1;
        uint4 c2 = *(const uint4*)rp2; const ushort* u2 = (const ushort*)&c2;
        #pragma unroll
        for (int j=0;j<8;++j){ v1[r][j+1] = u2f(u1[j]); v2[r][j+1] = u2f(u2[j]); }
        v1[r][0] = (px>0)   ? u2f(rp1[-1]) : 0.f;
        v1[r][9] = (px<120) ? u2f(rp1[8])  : 0.f;
        v2[r][0] = (px>0)   ? u2f(rp2[-1]) : 0.f;
        v2[r][9] = (px<120) ? u2f(rp2[8])  : 0.f;
      }
    }
    #pragma unroll
    for (int j=0;j<8;++j){
      float d1=0.f, d2=0.f;
      #pragma unroll
      for (int r=0;r<3;++r)
        #pragma unroll
        for (int dx=0;dx<3;++dx){
          d1 = fmaf(w1[r*3+dx], v1[r][j+dx], d1);
          d2 = fmaf(w2[r*3+dx], v2[r][j+dx], d2);
        }
      o8[j] = f2u(gelu_exact(d1)*d2);
    }
  } else {
    #pragma unroll
    for (int j=0;j<8;++j) o8[j] = 0;
  }
  #pragma unroll
  for (int j=0;j<8;++j){
    int row = xo + j;
    lt[row][c ^ (((row>>3)&3)<<3)] = o8[j];
  }
  __syncthreads();
  int ptl = t>>6, gfr = (t>>4)&3, cf = t&15;
  int rrow = ptl*16 + cf;
  int oct = gfr ^ ((rrow>>3)&3);
  uint4 vv = *(const uint4*)&lt[rrow][oct*8];
  int pt = (l0>>4) + ptl;
  *(uint4*)(gf + (size_t)b*512*L + ((size_t)(pt*16 + st)*64 + gfr*16 + cf)*8) = vv;
}

extern "C" void kernel_launch(void* const* d_in, const int* in_sizes, int n_in,
                              void* d_out, int out_size, void* d_ws, size_t ws_size,
                              hipStream_t stream){
  (void)in_sizes; (void)n_in; (void)out_size; (void)ws_size;
  const float* lr    = (const float*)d_in[0];
  const float* ref   = (const float*)d_in[1];
  const float* ln1w  = (const float*)d_in[2];
  const float* ln1b  = (const float*)d_in[3];
  const float* lnrw  = (const float*)d_in[4];
  const float* lnrb  = (const float*)d_in[5];
  const float* ln2w  = (const float*)d_in[6];
  const float* ln2b  = (const float*)d_in[7];
  const float* Wq    = (const float*)d_in[8];
  const float* qdw   = (const float*)d_in[9];
  const float* Wkv   = (const float*)d_in[10];
  const float* kvdw  = (const float*)d_in[11];
  const float* Wproj = (const float*)d_in[12];
  const float* Wca   = (const float*)d_in[13];
  const float* temp  = (const float*)d_in[14];
  const float* Wpin  = (const float*)d_in[15];
  const float* ffndw = (const float*)d_in[16];
  const float* Wpout = (const float*)d_in[17];
  float* out = (float*)d_out;

  char* ws = (char*)d_ws;
  size_t off = 0;
  auto alloc = [&](size_t bytes)->void*{ void* p = ws + off; off += (bytes + 255) & ~(size_t)255; return p; };

  ushort* Aqf    = (ushort*)alloc((size_t)192*192*2);
  ushort* Akvf   = (ushort*)alloc((size_t)384*192*2);
  ushort* Apinf  = (ushort*)alloc((size_t)1024*192*2);
  ushort* Apoutf = (ushort*)alloc((size_t)192*512*2);
  ushort* Mtf    = (ushort*)alloc((size_t)BATCH*192*192*2);
  float* Aqv  = (float*)alloc(192*4);   float* Bqv  = (float*)alloc(192*4);
  float* Akvv = (float*)alloc(384*4);   float* Bkvv = (float*)alloc(384*4);
  float* Apinv= (float*)alloc(1024*4);  float* Bpinv= (float*)alloc(1024*4);
  float* mu_lr = (float*)alloc((size_t)BL*4);  float* rs_lr = (float*)alloc((size_t)BL*4);
  float* mu_rf = (float*)alloc((size_t)BL*4);  float* rs_rf = (float*)alloc((size_t)BL*4);
  float* mu_o  = (float*)alloc((size_t)BL*4);  float* rs_o  = (float*)alloc((size_t)BL*4);
  // zero-init region: qss|kss|sum_o|ssq_o contiguous -> ONE memset
  float* qss   = (float*)alloc((size_t)BATCH*C0*4);      // 1536 B (256-mult)
  float* kss   = (float*)alloc((size_t)BATCH*C0*4);      // 1536 B
  float* sum_o = (float*)alloc((size_t)BL*4);            // 131072 B
  float* ssq_o = (float*)alloc((size_t)BL*4);            // 131072 B
  float* S     = (float*)alloc((size_t)BATCH*NH*CHN*CHN*4); (void)S;
  float* attnF = (float*)alloc((size_t)BATCH*NH*CHN*CHN*4);
  char*  pool  = (char*)alloc((size_t)104857600);

  // region map (sequential reuse):
  ushort* LRf    = (ushort*)(pool);                    // [0, 12.6M)
  ushort* REFf   = (ushort*)(pool + 12582912);         // [12.6, 25.2)
  ushort* q_pre  = (ushort*)(pool + 25165824);         // [25.2, 37.8)
  ushort* kv_pre = (ushort*)(pool + 37748736);         // [37.8, 63.0)
  ushort* qb     = (ushort*)(pool + 62914560);         // [63.0, 75.6)
  ushort* kvb_k  = (ushort*)(pool + 75497472);         // [75.6, 88.1)  k-rows only
  ushort* Vf     = (ushort*)(pool + 88080384);         // [88.1, 100.7) frag-packed v
  float*  Pp     = (float*) (pool);                    // 9.4M over LRf (dead after GEMMs)
  ushort* OUTf   = (ushort*)(pool);                    // 12.6M over Pp
  ushort* hidden = (ushort*)(pool + 33554432);         // 66.8M over kv_pre..Vf
  ushort* Gf     = (ushort*)(pool);                    // 33.5M over OUTf+REFf+q_pre

  hipMemsetAsync(qss, 0, (size_t)(1536 + 1536 + 131072 + 131072), stream);

  // unified weight prep
  prep_all_k<<<1591,256,0,stream>>>(Wq, ln1w, ln1b, Aqf, Aqv, Bqv,
                                    Wkv, lnrw, lnrb, Akvf, Akvv, Bkvv,
                                    Wpin, ln2w, ln2b, Apinf, Apinv, Bpinv,
                                    Wpout, Apoutf);

  // LN stats + frag-packed mirrors (lr and ref in one launch)
  ln_stats3_k<<<dim3(BL/256,2),256,0,stream>>>(lr, ref, mu_lr, rs_lr, mu_rf, rs_rf, LRf, REFf);

  // fused LN + 1x1 conv GEMMs
  gemm5_k<0,1,6,128><<<dim3(256,3),256,0,stream>>>(Aqf, 0, LRf, (size_t)C0*L,
      mu_lr, rs_lr, Aqv, Bqv, nullptr, q_pre, 192, 192, nullptr, nullptr, nullptr);
  gemm5_k<0,2,6,128><<<dim3(256,3),256,0,stream>>>(Akvf, 0, REFf, (size_t)C0*L,
      mu_rf, rs_rf, Akvv, Bkvv, nullptr, kv_pre, 384, 384, nullptr, nullptr, nullptr);

  // depthwise convs: q+k in one launch (row-major + ss), v direct frag-packed
  dwconvQK_k<<<6144,256,0,stream>>>(q_pre, kv_pre, qdw, kvdw, qb, kvb_k, qss, kss);
  dwconvV_k<<<dim3(256,6,2),256,0,stream>>>(kv_pre, kvdw, Vf);

  // attention core
  qk_mfma_k<<<dim3(KSPL, BATCH*NH),64,0,stream>>>(qb, kvb_k, Pp);
  gating_k<<<BATCH*NH*CHN,64,0,stream>>>(Pp, qss, kss, temp, Wca, attnF);
  mtf_k<<<288,256,0,stream>>>(Wproj, attnF, Mtf);

  // out = lr + Mt.v  (+ frag-packed OUTf + LN-stat atomics fused)
  gemm5_k<3,1,6,128><<<dim3(256,3),256,0,stream>>>(Mtf, 192*192, Vf, (size_t)C0*L,
      nullptr, nullptr, nullptr, nullptr, lr, out, 192, 192, OUTf, sum_o, ssq_o);
  finln_k<<<BL/256,256,0,stream>>>(sum_o, ssq_o, mu_o, rs_o);

  // GDFN
  gemm5_k<0,2,6,128><<<dim3(256,8),256,0,stream>>>(Apinf, 0, OUTf, (size_t)C0*L,
      mu_o, rs_o, Apinv, Bpinv, nullptr, hidden, 1020, 1020, nullptr, nullptr, nullptr);
  ffn8f_k<<<dim3(256,16,2),256,0,stream>>>(hidden, ffndw, Gf);
  gemm5_k<2,1,16,128><<<dim3(256,3),256,0,stream>>>(Apoutf, 0, Gf, (size_t)512*L,
      nullptr, nullptr, nullptr, nullptr, nullptr, out, 192, 192, nullptr, nullptr, nullptr);
}

// Round 14
// 241.106 us; speedup vs baseline: 1.6691x; 1.0973x over previous
//
#include <hip/hip_runtime.h>
#include <hip/hip_bf16.h>
#include <math.h>

#define L     16384
#define IMG   128
#define BATCH 2
#define C0    192
#define NH    4
#define CHN   48
#define HID   510
#define HID2  1020
#define BL    (BATCH*L)
#define KSPL  128

typedef float  f32x4  __attribute__((ext_vector_type(4)));
typedef __bf16 bf16x8 __attribute__((ext_vector_type(8)));

union UB16 { uint4 u; bf16x8 v; };

__device__ __forceinline__ bf16x8 ld_bf8(const ushort* p){ UB16 x; x.u = *(const uint4*)p; return x.v; }
__device__ __forceinline__ f32x4 mfma16(bf16x8 a, bf16x8 b, f32x4 c){
  return __builtin_amdgcn_mfma_f32_16x16x32_bf16(a, b, c, 0, 0, 0);
}
__device__ __forceinline__ float u2f(ushort u){ union{unsigned u; float f;} x; x.u = ((unsigned)u)<<16; return x.f; }
__device__ __forceinline__ ushort f2u(float f){ __hip_bfloat16 h = __float2bfloat16(f); return *reinterpret_cast<ushort*>(&h); }
__device__ __forceinline__ float gelu_exact(float x){ return 0.5f*x*(1.0f+erff(x*0.70710678118654752f)); }

// ---------------- bodies for the unified prep kernel ----------------
__device__ __forceinline__ void packwf_body(const float* __restrict__ W, const float* __restrict__ lnw,
                                            ushort* __restrict__ out, int Csrc, int O, int KS,
                                            int idx, int total){
  if (idx >= total) return;
  int j = idx & 7; int t = idx >> 3;
  int lane = t & 63; t >>= 6;
  int st = t % KS; int mt = t / KS;
  int m = mt*16 + (lane & 15);
  int k = st*32 + (lane >> 4)*8 + j;
  float v = 0.f;
  if (m < O && k < Csrc){ v = W[(size_t)m*Csrc + k]; if (lnw) v *= lnw[k]; }
  out[idx] = f2u(v);
}
__device__ __forceinline__ void prepab_body(const float* __restrict__ W, const float* __restrict__ lnw,
                                            const float* __restrict__ lnb, float* __restrict__ A,
                                            float* __restrict__ Bv, int Cc, int O, int Opad, int o){
  if (o >= Opad) return;
  float a=0.f,b=0.f;
  if (o < O){
    const float* wr = W + (size_t)o*Cc;
    for (int c=0;c<Cc;++c){ float w=wr[c]; a = fmaf(w, lnw[c], a); b = fmaf(w, lnb[c], b); }
  }
  A[o]=a; Bv[o]=b;
}
__device__ __forceinline__ void ln_body(const float* __restrict__ x, float* __restrict__ mu,
                                        float* __restrict__ rsig, ushort* __restrict__ xf, int pos){
  int b = pos >> 14, l = pos & (L-1);
  const float* xp = x + (size_t)b*C0*L + l;
  ushort* base = xf + (size_t)b*C0*L;
  int pt = l >> 4, c16 = l & 15;
  float s=0.f, ss=0.f;
  #pragma unroll
  for (int st=0; st<6; ++st)
    #pragma unroll
    for (int g=0; g<4; ++g){
      ushort u8[8];
      #pragma unroll
      for (int j=0;j<8;++j){
        float v = xp[(size_t)(st*32 + g*8 + j)*L];
        s += v; ss += v*v; u8[j] = f2u(v);
      }
      *(uint4*)(base + ((size_t)(pt*6+st)*64 + g*16 + c16)*8) = *(const uint4*)u8;
    }
  float m = s*(1.f/C0);
  float var = ss*(1.f/C0) - m*m;
  mu[pos]=m; rsig[pos]=rsqrtf(var + 1e-5f);
}

// prep_all: weight packs + prepab + zero-init + both LN-stat/mirror passes (one launch)
__global__ void prep_all_k(const float* Wq, const float* ln1w, const float* ln1b, ushort* Aqf, float* Aqv, float* Bqv,
                           const float* Wkv, const float* lnrw, const float* lnrb, ushort* Akvf, float* Akvv, float* Bkvv,
                           const float* Wpin, const float* ln2w, const float* ln2b, ushort* Apinf, float* Apinv, float* Bpinv,
                           const float* Wpout, ushort* Apoutf,
                           float* zbase,
                           const float* lr, const float* ref,
                           float* mu_lr, float* rs_lr, float* mu_rf, float* rs_rf,
                           ushort* LRf, ushort* REFf){
  int bx = blockIdx.x, tid = threadIdx.x;
  if (bx < 144)        packwf_body(Wq,   ln1w, Aqf,   192, 192, 6,  bx*256+tid,        36864);
  else if (bx < 432)   packwf_body(Wkv,  lnrw, Akvf,  192, 384, 6,  (bx-144)*256+tid,  73728);
  else if (bx < 1200)  packwf_body(Wpin, ln2w, Apinf, 192, 1020, 6, (bx-432)*256+tid,  196608);
  else if (bx < 1584)  packwf_body(Wpout, nullptr, Apoutf, 510, 192, 16, (bx-1200)*256+tid, 98304);
  else if (bx == 1584) prepab_body(Wq,  ln1w, ln1b, Aqv,  Bqv,  192, 192, 192,  tid);
  else if (bx < 1587)  prepab_body(Wkv, lnrw, lnrb, Akvv, Bkvv, 192, 384, 384,  (bx-1585)*256+tid);
  else if (bx < 1591)  prepab_body(Wpin,ln2w, ln2b, Apinv,Bpinv,192, 1020, 1024,(bx-1587)*256+tid);
  else if (bx < 1850){ int idx = (bx-1591)*256 + tid; if (idx < 66304) zbase[idx] = 0.f; }
  else {
    int r = bx - 1850;
    int z = r >> 7;
    int pos = (r & 127)*256 + tid;
    ln_body(z ? ref : lr, z ? mu_rf : mu_lr, z ? rs_rf : rs_lr, z ? REFf : LRf, pos);
  }
}

// ---------------- gemm5: barrier-free streaming MFMA GEMM ----------------
// WR=2: 128x128 tile (4 waves 2x2). WR=1: 64x128 (4 waves, 32 cols each).
// EPI 0: LN bf16 out via mu/rs arrays (LDS bounce)
// EPI 6: LN bf16 out via RAW sum/ss arrays (mu/rs computed inline)
// EPI 4: v=res+acc -> bf16 frag-packed outf + per-position sum/ss atomics (no f32 out)  [WR=1]
// EPI 5: final f32 out = u2f(outf gather) + acc                                         [WR=1]
template<int EPI, int WR, int KS, int BN>
__global__ __launch_bounds__(256, WR==2?3:4) void gemm5_k(
    const ushort* __restrict__ Af, int aBS,
    const ushort* __restrict__ Xf, size_t xBS,
    const float* __restrict__ mu, const float* __restrict__ rs,
    const float* __restrict__ Avec, const float* __restrict__ Bvec,
    const float* __restrict__ res,
    void* __restrict__ outp, int Orows, int Ovalid,
    ushort* __restrict__ outf, float* __restrict__ sum_acc, float* __restrict__ ss_acc)
{
  constexpr int BM  = WR*64;
  constexpr int NF  = (WR==2) ? 4 : (BN/64);
  constexpr int PB  = L/BN;
  constexpr int BLD = BN+8;
  constexpr int NSH = (EPI==0||EPI==6)? BM*BLD : (EPI==4 ? BN*72 : 64);
  __shared__ ushort bb[NSH];

  const int tid=threadIdx.x, lane=tid&63, w=tid>>6;
  const int g16=lane>>4, c16=lane&15;
  const int cpx = gridDim.x>>3;
  const int p = (blockIdx.x&7)*cpx + (blockIdx.x>>3);   // XCD-bijective
  const int b = p / PB;
  const int l0 = (p - b*PB)*BN;
  const int mbase = blockIdx.y*BM;
  const int wr = (WR==2)? (w>>1)*64 : 0;
  const int wc = (WR==2)? (w&1)*64 : w*(BN/4);
  const int mt0 = (mbase+wr)>>4;
  const int pt0 = (l0+wc)>>4;

  const ushort* Ap = Af + (size_t)b*aBS + ((size_t)(mt0*KS)*64 + lane)*8;
  const ushort* Bp = Xf + (size_t)b*xBS + ((size_t)(pt0*KS)*64 + lane)*8;

  f32x4 acc[4][NF];
  #pragma unroll
  for (int mi=0;mi<4;++mi)
    #pragma unroll
    for (int ni=0;ni<NF;++ni){ f32x4 z={0.f,0.f,0.f,0.f}; acc[mi][ni]=z; }

  bf16x8 ar[2][4], br[2][NF];
  #pragma unroll
  for (int i=0;i<4;++i) ar[0][i] = ld_bf8(Ap + (size_t)(i*KS)*512);
  #pragma unroll
  for (int i=0;i<NF;++i) br[0][i] = ld_bf8(Bp + (size_t)(i*KS)*512);
  #pragma unroll
  for (int st=0; st<KS; ++st){
    const int cur = st&1, nxt = cur^1;
    if (st+1 < KS){
      #pragma unroll
      for (int i=0;i<4;++i)  ar[nxt][i] = ld_bf8(Ap + (size_t)(i*KS + st+1)*512);
      #pragma unroll
      for (int i=0;i<NF;++i) br[nxt][i] = ld_bf8(Bp + (size_t)(i*KS + st+1)*512);
    }
    #pragma unroll
    for (int mi=0;mi<4;++mi)
      #pragma unroll
      for (int ni=0;ni<NF;++ni)
        acc[mi][ni] = mfma16(ar[cur][mi], br[cur][ni], acc[mi][ni]);
  }

  if (EPI==0 || EPI==6){
    #pragma unroll
    for (int ni=0;ni<NF;++ni){
      int nl = wc + ni*16 + c16;
      int posl = b*L + l0 + nl;
      float muv, rsv;
      if (EPI==0){ muv = mu[posl]; rsv = rs[posl]; }
      else {
        float sm = mu[posl]*(1.f/C0);
        float vq = rs[posl]*(1.f/C0) - sm*sm;
        muv = sm; rsv = rsqrtf(vq + 1e-5f);
      }
      #pragma unroll
      for (int mi=0;mi<4;++mi)
        #pragma unroll
        for (int r=0;r<4;++r){
          int ro = wr + mi*16 + g16*4 + r;
          int o  = mbase + ro;
          bb[ro*BLD + nl] = f2u(rsv*(acc[mi][ni][r] - muv*Avec[o]) + Bvec[o]);
        }
    }
    __syncthreads();
    constexpr int SEG = BN/64;
    constexpr int JOBS = BM*SEG;
    if (tid < JOBS){
      int row = tid/SEG, seg = tid%SEG;
      if (mbase + row < Ovalid){
        ushort* dst = (ushort*)outp + ((size_t)b*Orows + mbase + row)*L + l0 + seg*64;
        const ushort* src = &bb[row*BLD + seg*64];
        #pragma unroll
        for (int i=0;i<8;++i) *(uint4*)(dst + i*8) = *(const uint4*)(src + i*8);
      }
    }
  } else if (EPI==4){
    #pragma unroll
    for (int ni=0;ni<NF;++ni){
      int nl = wc + ni*16 + c16;
      int posl = b*L + l0 + nl;
      size_t cbase = ((size_t)b*Orows + mbase)*L + l0 + nl;
      float s1=0.f, s2=0.f;
      #pragma unroll
      for (int mi=0;mi<4;++mi)
        #pragma unroll
        for (int r=0;r<4;++r){
          int ro = mi*16 + g16*4 + r;
          float v = res[cbase + (size_t)ro*L] + acc[mi][ni][r];
          s1 += v; s2 += v*v;
          bb[nl*72 + ro] = f2u(v);
        }
      s1 += __shfl_xor(s1,16,64); s1 += __shfl_xor(s1,32,64);
      s2 += __shfl_xor(s2,16,64); s2 += __shfl_xor(s2,32,64);
      if (g16==0){ atomicAdd(&sum_acc[posl], s1); atomicAdd(&ss_acc[posl], s2); }
    }
    __syncthreads();
    constexpr int PTS = BN/16;
    int ph  = tid >> 7;
    int rm  = tid & 127;
    int stl = rm >> 6;
    int gf  = (rm >> 4) & 3;
    int cf  = rm & 15;
    int stg = (mbase >> 5) + stl;
    #pragma unroll
    for (int pp=0; pp<PTS/2; ++pp){
      int ptl = ph*(PTS/2) + pp;
      int nl  = ptl*16 + cf;
      uint4 v = *(const uint4*)&bb[nl*72 + stl*32 + gf*8];
      int ptg = (l0 >> 4) + ptl;
      *(uint4*)(outf + (size_t)b*C0*L + ((size_t)(ptg*6 + stg)*64 + gf*16 + cf)*8) = v;
    }
  } else { // EPI==5: final out = u2f(OUTf) + acc
    const ushort* ofb = outf + (size_t)b*C0*L;
    #pragma unroll
    for (int ni=0;ni<NF;++ni){
      int nl = wc + ni*16 + c16;
      int l  = l0 + nl;
      int pt = l >> 4, cc = l & 15;
      #pragma unroll
      for (int mi=0;mi<4;++mi)
        #pragma unroll
        for (int r=0;r<4;++r){
          int o = mbase + mi*16 + g16*4 + r;
          ushort u = ofb[((size_t)(pt*6 + (o>>5))*64 + ((o>>3)&3)*16 + cc)*8 + (o&7)];
          ((float*)outp)[((size_t)b*Orows + o)*L + l] = u2f(u) + acc[mi][ni][r];
        }
    }
  }
}

// ---------------- merged depthwise: q+k row-major (+ss) and v frag-packed ----------------
__global__ __launch_bounds__(256) void dwall_k(const ushort* __restrict__ qpre, const ushort* __restrict__ kvpre,
    const float* __restrict__ qdw, const float* __restrict__ kvdw,
    ushort* __restrict__ qb, ushort* __restrict__ kb,
    float* __restrict__ qss, float* __restrict__ kss,
    ushort* __restrict__ vf){
  __shared__ ushort lt[64][40];
  __shared__ float red[4];
  int bx = blockIdx.x;
  if (bx < 6144){
    bool isK = bx >= 3072;
    const ushort* in = isK ? kvpre : qpre;
    size_t inBS = isK ? (size_t)384*L : (size_t)192*L;
    const float* w9 = isK ? kvdw : qdw;
    ushort* out = isK ? kb : qb;
    float* ss = isK ? kss : qss;
    int e  = (isK ? bx-3072 : bx)*256 + threadIdx.x;
    int bc = e >> 11;
    int p  = (e & 2047) * 8;
    int c  = bc % 192, b = bc / 192;
    int y  = p >> 7, x0 = p & 127;
    const ushort* ip = in + (size_t)b*inBS + (size_t)c*L;
    float w[9];
    #pragma unroll
    for (int i=0;i<9;++i) w[i] = w9[c*9+i];
    float v[3][10];
    #pragma unroll
    for (int r=0;r<3;++r){
      int yy = y + r - 1;
      if ((unsigned)yy >= IMG){
        #pragma unroll
        for (int j=0;j<10;++j) v[r][j]=0.f;
      } else {
        const ushort* rp = ip + yy*IMG + x0;
        uint4 cv = *(const uint4*)rp; const ushort* us = (const ushort*)&cv;
        #pragma unroll
        for (int j=0;j<8;++j) v[r][j+1] = u2f(us[j]);
        v[r][0] = (x0>0)   ? u2f(rp[-1]) : 0.f;
        v[r][9] = (x0<120) ? u2f(rp[8])  : 0.f;
      }
    }
    float sq = 0.f; ushort o8[8];
    #pragma unroll
    for (int j=0;j<8;++j){
      float a = 0.f;
      #pragma unroll
      for (int r=0;r<3;++r)
        #pragma unroll
        for (int dx=0;dx<3;++dx) a = fmaf(w[r*3+dx], v[r][j+dx], a);
      o8[j] = f2u(a); sq += a*a;
    }
    *(uint4*)(out + (size_t)b*(size_t)192*L + (size_t)c*L + p) = *(const uint4*)o8;
    #pragma unroll
    for (int off=32; off>0; off>>=1) sq += __shfl_xor(sq, off, 64);
    int wid = threadIdx.x >> 6;
    if ((threadIdx.x & 63)==0) red[wid]=sq;
    __syncthreads();
    if (threadIdx.x==0) atomicAdd(&ss[b*192 + c], red[0]+red[1]+red[2]+red[3]);
  } else {
    int rr = bx - 6144;
    int xs = rr & 255;
    int st = (rr >> 8) % 6;
    int b  = rr / 1536;
    int chunk = ((xs & 7) << 5) | (xs >> 3);        // XCD-contiguous y-slices
    int t = threadIdx.x;
    int c = t >> 3, xo = (t & 7)*8;
    int l0 = chunk*64;
    int y = l0 >> 7, px = (l0 & 127) + xo;
    int gc = st*32 + c;
    const ushort* ip = kvpre + ((size_t)b*384 + C0 + gc)*L;
    const float* wp = kvdw + (size_t)(C0+gc)*9;
    float w[9];
    #pragma unroll
    for (int i=0;i<9;++i) w[i] = wp[i];
    float v[3][10];
    #pragma unroll
    for (int r=0;r<3;++r){
      int yy = y + r - 1;
      if ((unsigned)yy >= IMG){
        #pragma unroll
        for (int j=0;j<10;++j) v[r][j]=0.f;
      } else {
        const ushort* rp = ip + yy*IMG + px;
        uint4 cv = *(const uint4*)rp; const ushort* us = (const ushort*)&cv;
        #pragma unroll
        for (int j=0;j<8;++j) v[r][j+1] = u2f(us[j]);
        v[r][0] = (px>0)   ? u2f(rp[-1]) : 0.f;
        v[r][9] = (px<120) ? u2f(rp[8])  : 0.f;
      }
    }
    #pragma unroll
    for (int j=0;j<8;++j){
      float a = 0.f;
      #pragma unroll
      for (int r=0;r<3;++r)
        #pragma unroll
        for (int dx=0;dx<3;++dx) a = fmaf(w[r*3+dx], v[r][j+dx], a);
      int row = xo + j;
      lt[row][c ^ (((row>>3)&3)<<3)] = f2u(a);
    }
    __syncthreads();
    int ptl = t>>6, gf = (t>>4)&3, cf = t&15;
    int rrow = ptl*16 + cf;
    int oct = gf ^ ((rrow>>3)&3);
    uint4 vv = *(const uint4*)&lt[rrow][oct*8];
    int pt = (l0>>4) + ptl;
    *(uint4*)(vf + (size_t)b*C0*L + ((size_t)(pt*6 + st)*64 + gf*16 + cf)*8) = vv;
  }
}

// ---------------- QK^T via MFMA, k-split over L ----------------
__global__ __launch_bounds__(64) void qk_mfma_k(const ushort* __restrict__ qb, const ushort* __restrict__ kb,
                                                float* __restrict__ P){
  int ks = blockIdx.x, bh = blockIdx.y;
  int b = bh >> 2, h = bh & 3;
  int lane = threadIdx.x, g16 = lane>>4, c16 = lane&15;
  const ushort* qbase = qb + ((size_t)b*C0 + h*CHN)*L;
  const ushort* kbse  = kb + ((size_t)b*C0 + h*CHN)*L;
  f32x4 acc[3][3];
  #pragma unroll
  for (int i=0;i<3;++i)
    #pragma unroll
    for (int j=0;j<3;++j){ f32x4 z={0.f,0.f,0.f,0.f}; acc[i][j]=z; }
  int k0 = ks * (L/KSPL);
  for (int kk=0; kk<(L/KSPL)/32; ++kk){
    int kb2 = k0 + kk*32;
    bf16x8 af[3], bv[3];
    #pragma unroll
    for (int i=0;i<3;++i){
      af[i] = ld_bf8(qbase + (size_t)(i*16+c16)*L + kb2 + g16*8);
      bv[i] = ld_bf8(kbse  + (size_t)(i*16+c16)*L + kb2 + g16*8);
    }
    #pragma unroll
    for (int mi=0;mi<3;++mi)
      #pragma unroll
      for (int ni=0;ni<3;++ni)
        acc[mi][ni] = mfma16(af[mi], bv[ni], acc[mi][ni]);
  }
  float* Pp = P + ((size_t)ks*(BATCH*NH) + bh)*CHN*CHN;
  #pragma unroll
  for (int mi=0;mi<3;++mi)
    #pragma unroll
    for (int ni=0;ni<3;++ni)
      #pragma unroll
      for (int r=0;r<4;++r){
        int m = mi*16 + g16*4 + r, n = ni*16 + c16;
        Pp[m*CHN + n] = acc[mi][ni][r];
      }
}

// ---------------- Pp-reduce + softmax + gating + Wca modulation ----------------
__global__ __launch_bounds__(64) void gating_k(const float* __restrict__ Pp, const float* __restrict__ qss,
                         const float* __restrict__ kss, const float* __restrict__ temp,
                         const float* __restrict__ Wca, float* __restrict__ attnF){
  int blk = blockIdx.x;
  int c  = blk % CHN; int bh = blk / CHN;
  int h  = bh & 3, b = bh >> 2;
  int d  = threadIdx.x;
  bool act = (d < CHN);

  float sv = 0.f;
  if (act){
    const float* pr = Pp + (size_t)bh*CHN*CHN + c*CHN + d;
    for (int ks=0; ks<KSPL; ++ks) sv += pr[(size_t)ks*(BATCH*NH)*CHN*CHN];
  }

  float T  = temp[h];
  float nq = sqrtf(qss[b*C0 + h*CHN + c]);
  float rq = 1.f/fmaxf(nq, 1e-12f);
  float rk = 0.f;
  if (act){
    float nk = sqrtf(kss[b*C0 + h*CHN + d]);
    rk = 1.f/fmaxf(nk, 1e-12f);
  }
  float raw = act ? sv*rq*rk*T : -1e30f;

  float mx = raw;
  #pragma unroll
  for (int off=32; off>0; off>>=1) mx = fmaxf(mx, __shfl_xor(mx, off, 64));
  float e = act ? expf(raw - mx) : 0.f;
  float sum = e;
  #pragma unroll
  for (int off=32; off>0; off>>=1) sum += __shfl_xor(sum, off, 64);
  float a0 = e / sum;

  float r = fmaxf(raw, 0.f); r = r*r;
  float a1 = gelu_exact(r)*r;
  __shared__ float a1s[CHN];
  if (act) a1s[d] = a1;
  __syncthreads();

  if (!act) return;
  float s1 = 0.f, s2 = 0.f;
  const float* w1 = Wca + (size_t)d*CHN;
  const float* w2 = Wca + (size_t)(d+CHN)*CHN;
  #pragma unroll
  for (int j=0;j<CHN;++j){
    float aj = a1s[j];
    s1 = fmaf(w1[j], aj, s1);
    s2 = fmaf(w2[j], aj, s2);
  }
  attnF[((size_t)bh*CHN + c)*CHN + d] = a0*(1.f+s1) + s2;
}

// Mtf frag-packed
__global__ void mtf_k(const float* __restrict__ Wproj, const float* __restrict__ attnF,
                      ushort* __restrict__ Mtf){
  int idx = blockIdx.x*256 + threadIdx.x;
  if (idx >= BATCH*192*192) return;
  int j = idx & 7; int t = idx >> 3;
  int lane = t & 63; t >>= 6;
  int st = t % 6; t /= 6;
  int mt = t % 12; int b = t / 12;
  int o = mt*16 + (lane & 15);
  int d = st*32 + (lane >> 4)*8 + j;
  int h = d / CHN, dd = d % CHN;
  float s=0.f;
  for (int c=0;c<CHN;++c)
    s = fmaf(Wproj[(size_t)o*C0 + h*CHN + c],
             attnF[(((size_t)(b*NH+h))*CHN + c)*CHN + dd], s);
  Mtf[idx] = f2u(s);
}

// ---------------- GDFN dwconv + gelu gate -> frag-packed Gf, XCD-swizzled, XOR-LDS ----------------
__global__ __launch_bounds__(256) void ffn8f_k(const ushort* __restrict__ hidden, const float* __restrict__ w9,
                                               ushort* __restrict__ gf){
  __shared__ ushort lt[64][40];
  int xs = blockIdx.x;
  int chunk = ((xs & 7) << 5) | (xs >> 3);
  int st = blockIdx.y, b = blockIdx.z;
  int t = threadIdx.x;
  int c = t >> 3, xo = (t & 7)*8;
  int l0 = chunk*64;
  int y = l0 >> 7, px = (l0 & 127) + xo;
  int gc = st*32 + c;
  ushort o8[8];
  if (gc < HID){
    const ushort* i1 = hidden + ((size_t)b*HID2 + gc)*L;
    const ushort* i2 = i1 + (size_t)HID*L;
    float w1[9], w2[9];
    #pragma unroll
    for (int i=0;i<9;++i){ w1[i] = w9[gc*9+i]; w2[i] = w9[(HID+gc)*9+i]; }
    float v1[3][10], v2[3][10];
    #pragma unroll
    for (int r=0;r<3;++r){
      int yy = y + r - 1;
      if ((unsigned)yy >= IMG){
        #pragma unroll
        for (int j=0;j<10;++j){ v1[r][j]=0.f; v2[r][j]=0.f; }
      } else {
        const ushort* rp1 = i1 + yy*IMG + px;
        const ushort* rp2 = i2 + yy*IMG + px;
        uint4 c1 = *(const uint4*)rp1; const ushort* u1 = (const ushort*)&c1;
        uint4 c2 = *(const uint4*)rp2; const ushort* u2 = (const ushort*)&c2;
        #pragma unroll
        for (int j=0;j<8;++j){ v1[r][j+1] = u2f(u1[j]); v2[r][j+1] = u2f(u2[j]); }
        v1[r][0] = (px>0)   ? u2f(rp1[-1]) : 0.f;
        v1[r][9] = (px<120) ? u2f(rp1[8])  : 0.f;
        v2[r][0] = (px>0)   ? u2f(rp2[-1]) : 0.f;
        v2[r][9] = (px<120) ? u2f(rp2[8])  : 0.f;
      }
    }
    #pragma unroll
    for (int j=0;j<8;++j){
      float d1=0.f, d2=0.f;
      #pragma unroll
      for (int r=0;r<3;++r)
        #pragma unroll
        for (int dx=0;dx<3;++dx){
          d1 = fmaf(w1[r*3+dx], v1[r][j+dx], d1);
          d2 = fmaf(w2[r*3+dx], v2[r][j+dx], d2);
        }
      o8[j] = f2u(gelu_exact(d1)*d2);
    }
  } else {
    #pragma unroll
    for (int j=0;j<8;++j) o8[j] = 0;
  }
  #pragma unroll
  for (int j=0;j<8;++j){
    int row = xo + j;
    lt[row][c ^ (((row>>3)&3)<<3)] = o8[j];
  }
  __syncthreads();
  int ptl = t>>6, gfr = (t>>4)&3, cf = t&15;
  int rrow = ptl*16 + cf;
  int oct = gfr ^ ((rrow>>3)&3);
  uint4 vv = *(const uint4*)&lt[rrow][oct*8];
  int pt = (l0>>4) + ptl;
  *(uint4*)(gf + (size_t)b*512*L + ((size_t)(pt*16 + st)*64 + gfr*16 + cf)*8) = vv;
}

extern "C" void kernel_launch(void* const* d_in, const int* in_sizes, int n_in,
                              void* d_out, int out_size, void* d_ws, size_t ws_size,
                              hipStream_t stream){
  (void)in_sizes; (void)n_in; (void)out_size; (void)ws_size;
  const float* lr    = (const float*)d_in[0];
  const float* ref   = (const float*)d_in[1];
  const float* ln1w  = (const float*)d_in[2];
  const float* ln1b  = (const float*)d_in[3];
  const float* lnrw  = (const float*)d_in[4];
  const float* lnrb  = (const float*)d_in[5];
  const float* ln2w  = (const float*)d_in[6];
  const float* ln2b  = (const float*)d_in[7];
  const float* Wq    = (const float*)d_in[8];
  const float* qdw   = (const float*)d_in[9];
  const float* Wkv   = (const float*)d_in[10];
  const float* kvdw  = (const float*)d_in[11];
  const float* Wproj = (const float*)d_in[12];
  const float* Wca   = (const float*)d_in[13];
  const float* temp  = (const float*)d_in[14];
  const float* Wpin  = (const float*)d_in[15];
  const float* ffndw = (const float*)d_in[16];
  const float* Wpout = (const float*)d_in[17];
  float* out = (float*)d_out;

  char* ws = (char*)d_ws;
  size_t off = 0;
  auto alloc = [&](size_t bytes)->void*{ void* p = ws + off; off += (bytes + 255) & ~(size_t)255; return p; };

  ushort* Aqf    = (ushort*)alloc((size_t)192*192*2);
  ushort* Akvf   = (ushort*)alloc((size_t)384*192*2);
  ushort* Apinf  = (ushort*)alloc((size_t)1024*192*2);
  ushort* Apoutf = (ushort*)alloc((size_t)192*512*2);
  ushort* Mtf    = (ushort*)alloc((size_t)BATCH*192*192*2);
  float* Aqv  = (float*)alloc(192*4);   float* Bqv  = (float*)alloc(192*4);
  float* Akvv = (float*)alloc(384*4);   float* Bkvv = (float*)alloc(384*4);
  float* Apinv= (float*)alloc(1024*4);  float* Bpinv= (float*)alloc(1024*4);
  float* mu_lr = (float*)alloc((size_t)BL*4);  float* rs_lr = (float*)alloc((size_t)BL*4);
  float* mu_rf = (float*)alloc((size_t)BL*4);  float* rs_rf = (float*)alloc((size_t)BL*4);
  // zero-init region: qss|kss|sum_o|ssq_o contiguous (66304 floats)
  float* qss   = (float*)alloc((size_t)BATCH*C0*4);
  float* kss   = (float*)alloc((size_t)BATCH*C0*4);
  float* sum_o = (float*)alloc((size_t)BL*4);
  float* ssq_o = (float*)alloc((size_t)BL*4);
  float* attnF = (float*)alloc((size_t)BATCH*NH*CHN*CHN*4);
  char*  pool  = (char*)alloc((size_t)104857600);

  // region map (sequential reuse):
  ushort* LRf    = (ushort*)(pool);                    // [0, 12.6M)
  ushort* REFf   = (ushort*)(pool + 12582912);         // [12.6, 25.2)
  ushort* q_pre  = (ushort*)(pool + 25165824);         // [25.2, 37.8)
  ushort* kv_pre = (ushort*)(pool + 37748736);         // [37.8, 63.0)
  ushort* qb     = (ushort*)(pool + 62914560);         // [63.0, 75.6)
  ushort* kvb_k  = (ushort*)(pool + 75497472);         // [75.6, 88.1)  k-rows only
  ushort* Vf     = (ushort*)(pool + 88080384);         // [88.1, 100.7) frag-packed v
  float*  Pp     = (float*) (pool);                    // 9.4M over LRf (dead after q-GEMM)
  ushort* OUTf   = (ushort*)(pool);                    // 12.6M over Pp (dead after gating)
  ushort* hidden = (ushort*)(pool + 33554432);         // 66.8M over kv_pre..Vf
  ushort* Gf     = (ushort*)(pool + 12582912);         // 33.5M over REFf+q_pre (dead by ffn8f); OUTf stays live for pout

  // unified prep: weight packs + prepab + zero-init + LN stats/mirrors
  prep_all_k<<<2106,256,0,stream>>>(Wq, ln1w, ln1b, Aqf, Aqv, Bqv,
                                    Wkv, lnrw, lnrb, Akvf, Akvv, Bkvv,
                                    Wpin, ln2w, ln2b, Apinf, Apinv, Bpinv,
                                    Wpout, Apoutf,
                                    qss,
                                    lr, ref, mu_lr, rs_lr, mu_rf, rs_rf, LRf, REFf);

  // fused LN + 1x1 conv GEMMs
  gemm5_k<0,1,6,128><<<dim3(256,3),256,0,stream>>>(Aqf, 0, LRf, (size_t)C0*L,
      mu_lr, rs_lr, Aqv, Bqv, nullptr, q_pre, 192, 192, nullptr, nullptr, nullptr);
  gemm5_k<0,2,6,128><<<dim3(256,3),256,0,stream>>>(Akvf, 0, REFf, (size_t)C0*L,
      mu_rf, rs_rf, Akvv, Bkvv, nullptr, kv_pre, 384, 384, nullptr, nullptr, nullptr);

  // merged depthwise: q+k row-major (+ss) and v frag-packed
  dwall_k<<<9216,256,0,stream>>>(q_pre, kv_pre, qdw, kvdw, qb, kvb_k, qss, kss, Vf);

  // attention core
  qk_mfma_k<<<dim3(KSPL, BATCH*NH),64,0,stream>>>(qb, kvb_k, Pp);
  gating_k<<<BATCH*NH*CHN,64,0,stream>>>(Pp, qss, kss, temp, Wca, attnF);
  mtf_k<<<288,256,0,stream>>>(Wproj, attnF, Mtf);

  // lr2 = lr + Mt.v -> OUTf (bf16 frag) + LN-stat atomics only (no f32 out)
  gemm5_k<4,1,6,128><<<dim3(256,3),256,0,stream>>>(Mtf, 192*192, Vf, (size_t)C0*L,
      nullptr, nullptr, nullptr, nullptr, lr, nullptr, 192, 192, OUTf, sum_o, ssq_o);

  // GDFN: pin with inline LN-from-raw-stats
  gemm5_k<6,2,6,128><<<dim3(256,8),256,0,stream>>>(Apinf, 0, OUTf, (size_t)C0*L,
      sum_o, ssq_o, Apinv, Bpinv, nullptr, hidden, 1020, 1020, nullptr, nullptr, nullptr);
  ffn8f_k<<<dim3(256,16,2),256,0,stream>>>(hidden, ffndw, Gf);

  // final: out = u2f(OUTf) + Wpout.g
  gemm5_k<5,1,16,128><<<dim3(256,3),256,0,stream>>>(Apoutf, 0, Gf, (size_t)512*L,
      nullptr, nullptr, nullptr, nullptr, nullptr, out, 192, 192, OUTf, nullptr, nullptr);
}

// Round 17
// 231.187 us; speedup vs baseline: 1.7407x; 1.0429x over previous
//
#include <hip/hip_runtime.h>
#include <hip/hip_bf16.h>
#include <math.h>

#define L     16384
#define IMG   128
#define BATCH 2
#define C0    192
#define NH    4
#define CHN   48
#define HID   510
#define HID2  1020
#define BL    (BATCH*L)
#define KSPL  128

typedef float  f32x4  __attribute__((ext_vector_type(4)));
typedef __bf16 bf16x8 __attribute__((ext_vector_type(8)));

union UB16 { uint4 u; bf16x8 v; };

__device__ __forceinline__ bf16x8 ld_bf8(const ushort* p){ UB16 x; x.u = *(const uint4*)p; return x.v; }
__device__ __forceinline__ f32x4 mfma16(bf16x8 a, bf16x8 b, f32x4 c){
  return __builtin_amdgcn_mfma_f32_16x16x32_bf16(a, b, c, 0, 0, 0);
}
__device__ __forceinline__ float u2f(ushort u){ union{unsigned u; float f;} x; x.u = ((unsigned)u)<<16; return x.f; }
__device__ __forceinline__ ushort f2u(float f){ __hip_bfloat16 h = __float2bfloat16(f); return *reinterpret_cast<ushort*>(&h); }
__device__ __forceinline__ float gelu_exact(float x){ return 0.5f*x*(1.0f+erff(x*0.70710678118654752f)); }

// ---------------- bodies for the unified prep kernel ----------------
__device__ __forceinline__ void packwf_body(const float* __restrict__ W, const float* __restrict__ lnw,
                                            ushort* __restrict__ out, int Csrc, int O, int KS,
                                            int idx, int total){
  if (idx >= total) return;
  int j = idx & 7; int t = idx >> 3;
  int lane = t & 63; t >>= 6;
  int st = t % KS; int mt = t / KS;
  int m = mt*16 + (lane & 15);
  int k = st*32 + (lane >> 4)*8 + j;
  float v = 0.f;
  if (m < O && k < Csrc){ v = W[(size_t)m*Csrc + k]; if (lnw) v *= lnw[k]; }
  out[idx] = f2u(v);
}
__device__ __forceinline__ void prepab_body(const float* __restrict__ W, const float* __restrict__ lnw,
                                            const float* __restrict__ lnb, float* __restrict__ A,
                                            float* __restrict__ Bv, int Cc, int O, int Opad, int o){
  if (o >= Opad) return;
  float a=0.f,b=0.f;
  if (o < O){
    const float* wr = W + (size_t)o*Cc;
    for (int c=0;c<Cc;++c){ float w=wr[c]; a = fmaf(w, lnw[c], a); b = fmaf(w, lnb[c], b); }
  }
  A[o]=a; Bv[o]=b;
}
__device__ __forceinline__ void ln_body(const float* __restrict__ x, float* __restrict__ mu,
                                        float* __restrict__ rsig, ushort* __restrict__ xf, int pos){
  int b = pos >> 14, l = pos & (L-1);
  const float* xp = x + (size_t)b*C0*L + l;
  ushort* base = xf + (size_t)b*C0*L;
  int pt = l >> 4, c16 = l & 15;
  float s=0.f, ss=0.f;
  #pragma unroll
  for (int st=0; st<6; ++st)
    #pragma unroll
    for (int g=0; g<4; ++g){
      ushort u8[8];
      #pragma unroll
      for (int j=0;j<8;++j){
        float v = xp[(size_t)(st*32 + g*8 + j)*L];
        s += v; ss += v*v; u8[j] = f2u(v);
      }
      *(uint4*)(base + ((size_t)(pt*6+st)*64 + g*16 + c16)*8) = *(const uint4*)u8;
    }
  float m = s*(1.f/C0);
  float var = ss*(1.f/C0) - m*m;
  mu[pos]=m; rsig[pos]=rsqrtf(var + 1e-5f);
}

// prep_all: weight packs + prepab + zero-init + both LN-stat/mirror passes
__global__ void prep_all_k(const float* Wq, const float* ln1w, const float* ln1b, ushort* Aqf, float* Aqv, float* Bqv,
                           const float* Wkv, const float* lnrw, const float* lnrb, ushort* Akvf, float* Akvv, float* Bkvv,
                           const float* Wpin, const float* ln2w, const float* ln2b, ushort* Apinf, float* Apinv, float* Bpinv,
                           const float* Wpout, ushort* Apoutf,
                           float* zbase,
                           const float* lr, const float* ref,
                           float* mu_lr, float* rs_lr, float* mu_rf, float* rs_rf,
                           ushort* LRf, ushort* REFf){
  int bx = blockIdx.x, tid = threadIdx.x;
  if (bx < 144)        packwf_body(Wq,   ln1w, Aqf,   192, 192, 6,  bx*256+tid,        36864);
  else if (bx < 432)   packwf_body(Wkv,  lnrw, Akvf,  192, 384, 6,  (bx-144)*256+tid,  73728);
  else if (bx < 1200)  packwf_body(Wpin, ln2w, Apinf, 192, 1020, 6, (bx-432)*256+tid,  196608);
  else if (bx < 1584)  packwf_body(Wpout, nullptr, Apoutf, 510, 192, 16, (bx-1200)*256+tid, 98304);
  else if (bx == 1584) prepab_body(Wq,  ln1w, ln1b, Aqv,  Bqv,  192, 192, 192,  tid);
  else if (bx < 1587)  prepab_body(Wkv, lnrw, lnrb, Akvv, Bkvv, 192, 384, 384,  (bx-1585)*256+tid);
  else if (bx < 1591)  prepab_body(Wpin,ln2w, ln2b, Apinv,Bpinv,192, 1020, 1024,(bx-1587)*256+tid);
  else if (bx < 1850){ int idx = (bx-1591)*256 + tid; if (idx < 66304) zbase[idx] = 0.f; }
  else {
    int r = bx - 1850;
    int z = r >> 7;
    int pos = (r & 127)*256 + tid;
    ln_body(z ? ref : lr, z ? mu_rf : mu_lr, z ? rs_rf : rs_lr, z ? REFf : LRf, pos);
  }
}

// ---------------- merged q+kv LN-GEMM (all WR=1, one launch) ----------------
__global__ __launch_bounds__(256,4) void gemmqkv_k(
    const ushort* __restrict__ Aqf, const ushort* __restrict__ Akvf,
    const ushort* __restrict__ LRf, const ushort* __restrict__ REFf,
    const float* __restrict__ mu_lr, const float* __restrict__ rs_lr,
    const float* __restrict__ mu_rf, const float* __restrict__ rs_rf,
    const float* __restrict__ Aqv, const float* __restrict__ Bqv,
    const float* __restrict__ Akvv, const float* __restrict__ Bkvv,
    ushort* __restrict__ q_pre, ushort* __restrict__ kv_pre)
{
  constexpr int KS = 6, BN = 128, BLD = BN+8;
  __shared__ ushort bb[64*BLD];

  const bool isK = blockIdx.y >= 3;
  const int mbase = (isK ? (blockIdx.y-3) : blockIdx.y)*64;
  const ushort* Af = isK ? Akvf : Aqf;
  const ushort* Xf = isK ? REFf : LRf;
  const float* mu = isK ? mu_rf : mu_lr;
  const float* rs = isK ? rs_rf : rs_lr;
  const float* Avec = isK ? Akvv : Aqv;
  const float* Bvec = isK ? Bkvv : Bqv;
  ushort* outp = isK ? kv_pre : q_pre;
  const int Orows = isK ? 384 : 192;

  const int tid=threadIdx.x, lane=tid&63, w=tid>>6;
  const int g16=lane>>4, c16=lane&15;
  const int cpx = gridDim.x>>3;
  const int p = (blockIdx.x&7)*cpx + (blockIdx.x>>3);
  const int b = p >> 7;
  const int l0 = (p & 127)*BN;
  const int wc = w*32;
  const int mt0 = mbase>>4;
  const int pt0 = (l0+wc)>>4;

  const ushort* Ap = Af + ((size_t)(mt0*KS)*64 + lane)*8;
  const ushort* Bp = Xf + (size_t)b*((size_t)C0*L) + ((size_t)(pt0*KS)*64 + lane)*8;

  f32x4 acc[4][2];
  #pragma unroll
  for (int mi=0;mi<4;++mi)
    #pragma unroll
    for (int ni=0;ni<2;++ni){ f32x4 z={0.f,0.f,0.f,0.f}; acc[mi][ni]=z; }

  bf16x8 ar[2][4], br[2][2];
  #pragma unroll
  for (int i=0;i<4;++i) ar[0][i] = ld_bf8(Ap + (size_t)(i*KS)*512);
  #pragma unroll
  for (int i=0;i<2;++i) br[0][i] = ld_bf8(Bp + (size_t)(i*KS)*512);
  #pragma unroll
  for (int st=0; st<KS; ++st){
    const int cur = st&1, nxt = cur^1;
    if (st+1 < KS){
      #pragma unroll
      for (int i=0;i<4;++i) ar[nxt][i] = ld_bf8(Ap + (size_t)(i*KS + st+1)*512);
      #pragma unroll
      for (int i=0;i<2;++i) br[nxt][i] = ld_bf8(Bp + (size_t)(i*KS + st+1)*512);
    }
    #pragma unroll
    for (int mi=0;mi<4;++mi)
      #pragma unroll
      for (int ni=0;ni<2;++ni)
        acc[mi][ni] = mfma16(ar[cur][mi], br[cur][ni], acc[mi][ni]);
  }

  #pragma unroll
  for (int ni=0;ni<2;++ni){
    int nl = wc + ni*16 + c16;
    int posl = b*L + l0 + nl;
    float muv = mu[posl], rsv = rs[posl];
    #pragma unroll
    for (int mi=0;mi<4;++mi)
      #pragma unroll
      for (int r=0;r<4;++r){
        int ro = mi*16 + g16*4 + r;
        int o  = mbase + ro;
        bb[ro*BLD + nl] = f2u(rsv*(acc[mi][ni][r] - muv*Avec[o]) + Bvec[o]);
      }
  }
  __syncthreads();
  if (tid < 128){                       // 64 rows x 2 segs
    int row = tid >> 1, seg = tid & 1;
    ushort* dst = outp + ((size_t)b*Orows + mbase + row)*L + l0 + seg*64;
    const ushort* src = &bb[row*BLD + seg*64];
    #pragma unroll
    for (int i=0;i<8;++i) *(uint4*)(dst + i*8) = *(const uint4*)(src + i*8);
  }
}

// ---------------- gemm5: barrier-free streaming MFMA GEMM ----------------
// EPI 6: LN bf16 out via RAW sum/ss arrays (mu/rs computed inline)  [WR=2]
// EPI 4: v=u2f(resf gather)+acc -> bf16 frag outf + sum/ss atomics   [WR=1]
// EPI 5: final f32 out = u2f(outf gather) + acc                      [WR=1]
template<int EPI, int WR, int KS, int BN>
__global__ __launch_bounds__(256, WR==2?3:4) void gemm5_k(
    const ushort* __restrict__ Af, int aBS,
    const ushort* __restrict__ Xf, size_t xBS,
    const float* __restrict__ mu, const float* __restrict__ rs,
    const float* __restrict__ Avec, const float* __restrict__ Bvec,
    const ushort* __restrict__ resf,
    void* __restrict__ outp, int Orows, int Ovalid,
    ushort* __restrict__ outf, float* __restrict__ sum_acc, float* __restrict__ ss_acc)
{
  constexpr int BM  = WR*64;
  constexpr int NF  = (WR==2) ? 4 : (BN/64);
  constexpr int PB  = L/BN;
  constexpr int BLD = BN+8;
  constexpr int NSH = (EPI==6)? BM*BLD : (EPI==4 ? BN*72 : 64);
  __shared__ ushort bb[NSH];

  const int tid=threadIdx.x, lane=tid&63, w=tid>>6;
  const int g16=lane>>4, c16=lane&15;
  const int cpx = gridDim.x>>3;
  const int p = (blockIdx.x&7)*cpx + (blockIdx.x>>3);   // XCD-bijective
  const int b = p / PB;
  const int l0 = (p - b*PB)*BN;
  const int mbase = blockIdx.y*BM;
  const int wr = (WR==2)? (w>>1)*64 : 0;
  const int wc = (WR==2)? (w&1)*64 : w*(BN/4);
  const int mt0 = (mbase+wr)>>4;
  const int pt0 = (l0+wc)>>4;

  const ushort* Ap = Af + (size_t)b*aBS + ((size_t)(mt0*KS)*64 + lane)*8;
  const ushort* Bp = Xf + (size_t)b*xBS + ((size_t)(pt0*KS)*64 + lane)*8;

  f32x4 acc[4][NF];
  #pragma unroll
  for (int mi=0;mi<4;++mi)
    #pragma unroll
    for (int ni=0;ni<NF;++ni){ f32x4 z={0.f,0.f,0.f,0.f}; acc[mi][ni]=z; }

  bf16x8 ar[2][4], br[2][NF];
  #pragma unroll
  for (int i=0;i<4;++i) ar[0][i] = ld_bf8(Ap + (size_t)(i*KS)*512);
  #pragma unroll
  for (int i=0;i<NF;++i) br[0][i] = ld_bf8(Bp + (size_t)(i*KS)*512);
  #pragma unroll
  for (int st=0; st<KS; ++st){
    const int cur = st&1, nxt = cur^1;
    if (st+1 < KS){
      #pragma unroll
      for (int i=0;i<4;++i)  ar[nxt][i] = ld_bf8(Ap + (size_t)(i*KS + st+1)*512);
      #pragma unroll
      for (int i=0;i<NF;++i) br[nxt][i] = ld_bf8(Bp + (size_t)(i*KS + st+1)*512);
    }
    #pragma unroll
    for (int mi=0;mi<4;++mi)
      #pragma unroll
      for (int ni=0;ni<NF;++ni)
        acc[mi][ni] = mfma16(ar[cur][mi], br[cur][ni], acc[mi][ni]);
  }

  if (EPI==6){
    #pragma unroll
    for (int ni=0;ni<NF;++ni){
      int nl = wc + ni*16 + c16;
      int posl = b*L + l0 + nl;
      float sm = mu[posl]*(1.f/C0);
      float vq = rs[posl]*(1.f/C0) - sm*sm;
      float muv = sm, rsv = rsqrtf(vq + 1e-5f);
      #pragma unroll
      for (int mi=0;mi<4;++mi)
        #pragma unroll
        for (int r=0;r<4;++r){
          int ro = wr + mi*16 + g16*4 + r;
          int o  = mbase + ro;
          bb[ro*BLD + nl] = f2u(rsv*(acc[mi][ni][r] - muv*Avec[o]) + Bvec[o]);
        }
    }
    __syncthreads();
    constexpr int SEG = BN/64;
    constexpr int JOBS = BM*SEG;
    if (tid < JOBS){
      int row = tid/SEG, seg = tid%SEG;
      if (mbase + row < Ovalid){
        ushort* dst = (ushort*)outp + ((size_t)b*Orows + mbase + row)*L + l0 + seg*64;
        const ushort* src = &bb[row*BLD + seg*64];
        #pragma unroll
        for (int i=0;i<8;++i) *(uint4*)(dst + i*8) = *(const uint4*)(src + i*8);
      }
    }
  } else if (EPI==4){
    const ushort* rfb = resf + (size_t)b*C0*L;
    #pragma unroll
    for (int ni=0;ni<NF;++ni){
      int nl = wc + ni*16 + c16;
      int l  = l0 + nl;
      int posl = b*L + l;
      int pt = l >> 4, cc = l & 15;
      float s1=0.f, s2=0.f;
      #pragma unroll
      for (int mi=0;mi<4;++mi)
        #pragma unroll
        for (int r=0;r<4;++r){
          int ro = mi*16 + g16*4 + r;
          int o  = mbase + ro;   // GLOBAL channel (r15/r16 bug: used local ro here)
          ushort ur = rfb[((size_t)(pt*6 + (o>>5))*64 + ((o>>3)&3)*16 + cc)*8 + (o&7)];
          float v = u2f(ur) + acc[mi][ni][r];
          s1 += v; s2 += v*v;
          bb[nl*72 + ro] = f2u(v);
        }
      s1 += __shfl_xor(s1,16,64); s1 += __shfl_xor(s1,32,64);
      s2 += __shfl_xor(s2,16,64); s2 += __shfl_xor(s2,32,64);
      if (g16==0){ atomicAdd(&sum_acc[posl], s1); atomicAdd(&ss_acc[posl], s2); }
    }
    __syncthreads();
    constexpr int PTS = BN/16;
    int ph  = tid >> 7;
    int rm  = tid & 127;
    int stl = rm >> 6;
    int gf  = (rm >> 4) & 3;
    int cf  = rm & 15;
    int stg = (mbase >> 5) + stl;
    #pragma unroll
    for (int pp=0; pp<PTS/2; ++pp){
      int ptl = ph*(PTS/2) + pp;
      int nl  = ptl*16 + cf;
      uint4 v = *(const uint4*)&bb[nl*72 + stl*32 + gf*8];
      int ptg = (l0 >> 4) + ptl;
      *(uint4*)(outf + (size_t)b*C0*L + ((size_t)(ptg*6 + stg)*64 + gf*16 + cf)*8) = v;
    }
  } else { // EPI==5: final out = u2f(OUTf) + acc
    const ushort* ofb = outf + (size_t)b*C0*L;
    #pragma unroll
    for (int ni=0;ni<NF;++ni){
      int nl = wc + ni*16 + c16;
      int l  = l0 + nl;
      int pt = l >> 4, cc = l & 15;
      #pragma unroll
      for (int mi=0;mi<4;++mi)
        #pragma unroll
        for (int r=0;r<4;++r){
          int o = mbase + mi*16 + g16*4 + r;
          ushort u = ofb[((size_t)(pt*6 + (o>>5))*64 + ((o>>3)&3)*16 + cc)*8 + (o&7)];
          ((float*)outp)[((size_t)b*Orows + o)*L + l] = u2f(u) + acc[mi][ni][r];
        }
    }
  }
}

// ---------------- merged depthwise: q+k row-major (+ss) and v frag-packed ----------------
__global__ __launch_bounds__(256) void dwall_k(const ushort* __restrict__ qpre, const ushort* __restrict__ kvpre,
    const float* __restrict__ qdw, const float* __restrict__ kvdw,
    ushort* __restrict__ qb, ushort* __restrict__ kb,
    float* __restrict__ qss, float* __restrict__ kss,
    ushort* __restrict__ vf){
  __shared__ ushort lt[64][40];
  __shared__ float red[4];
  int bx = blockIdx.x;
  if (bx < 6144){
    bool isK = bx >= 3072;
    const ushort* in = isK ? kvpre : qpre;
    size_t inBS = isK ? (size_t)384*L : (size_t)192*L;
    const float* w9 = isK ? kvdw : qdw;
    ushort* out = isK ? kb : qb;
    float* ss = isK ? kss : qss;
    int e  = (isK ? bx-3072 : bx)*256 + threadIdx.x;
    int bc = e >> 11;
    int p  = (e & 2047) * 8;
    int c  = bc % 192, b = bc / 192;
    int y  = p >> 7, x0 = p & 127;
    const ushort* ip = in + (size_t)b*inBS + (size_t)c*L;
    float w[9];
    #pragma unroll
    for (int i=0;i<9;++i) w[i] = w9[c*9+i];
    float v[3][10];
    #pragma unroll
    for (int r=0;r<3;++r){
      int yy = y + r - 1;
      if ((unsigned)yy >= IMG){
        #pragma unroll
        for (int j=0;j<10;++j) v[r][j]=0.f;
      } else {
        const ushort* rp = ip + yy*IMG + x0;
        uint4 cv = *(const uint4*)rp; const ushort* us = (const ushort*)&cv;
        #pragma unroll
        for (int j=0;j<8;++j) v[r][j+1] = u2f(us[j]);
        v[r][0] = (x0>0)   ? u2f(rp[-1]) : 0.f;
        v[r][9] = (x0<120) ? u2f(rp[8])  : 0.f;
      }
    }
    float sq = 0.f; ushort o8[8];
    #pragma unroll
    for (int j=0;j<8;++j){
      float a = 0.f;
      #pragma unroll
      for (int r=0;r<3;++r)
        #pragma unroll
        for (int dx=0;dx<3;++dx) a = fmaf(w[r*3+dx], v[r][j+dx], a);
      o8[j] = f2u(a); sq += a*a;
    }
    *(uint4*)(out + (size_t)b*(size_t)192*L + (size_t)c*L + p) = *(const uint4*)o8;
    #pragma unroll
    for (int off=32; off>0; off>>=1) sq += __shfl_xor(sq, off, 64);
    int wid = threadIdx.x >> 6;
    if ((threadIdx.x & 63)==0) red[wid]=sq;
    __syncthreads();
    if (threadIdx.x==0) atomicAdd(&ss[b*192 + c], red[0]+red[1]+red[2]+red[3]);
  } else {
    int rr = bx - 6144;
    int xs = rr & 255;
    int st = (rr >> 8) % 6;
    int b  = rr / 1536;
    int chunk = ((xs & 7) << 5) | (xs >> 3);        // XCD-contiguous y-slices
    int t = threadIdx.x;
    int c = t >> 3, xo = (t & 7)*8;
    int l0 = chunk*64;
    int y = l0 >> 7, px = (l0 & 127) + xo;
    int gc = st*32 + c;
    const ushort* ip = kvpre + ((size_t)b*384 + C0 + gc)*L;
    const float* wp = kvdw + (size_t)(C0+gc)*9;
    float w[9];
    #pragma unroll
    for (int i=0;i<9;++i) w[i] = wp[i];
    float v[3][10];
    #pragma unroll
    for (int r=0;r<3;++r){
      int yy = y + r - 1;
      if ((unsigned)yy >= IMG){
        #pragma unroll
        for (int j=0;j<10;++j) v[r][j]=0.f;
      } else {
        const ushort* rp = ip + yy*IMG + px;
        uint4 cv = *(const uint4*)rp; const ushort* us = (const ushort*)&cv;
        #pragma unroll
        for (int j=0;j<8;++j) v[r][j+1] = u2f(us[j]);
        v[r][0] = (px>0)   ? u2f(rp[-1]) : 0.f;
        v[r][9] = (px<120) ? u2f(rp[8])  : 0.f;
      }
    }
    #pragma unroll
    for (int j=0;j<8;++j){
      float a = 0.f;
      #pragma unroll
      for (int r=0;r<3;++r)
        #pragma unroll
        for (int dx=0;dx<3;++dx) a = fmaf(w[r*3+dx], v[r][j+dx], a);
      int row = xo + j;
      lt[row][c ^ (((row>>3)&3)<<3)] = f2u(a);
    }
    __syncthreads();
    int ptl = t>>6, gf = (t>>4)&3, cf = t&15;
    int rrow = ptl*16 + cf;
    int oct = gf ^ ((rrow>>3)&3);
    uint4 vv = *(const uint4*)&lt[rrow][oct*8];
    int pt = (l0>>4) + ptl;
    *(uint4*)(vf + (size_t)b*C0*L + ((size_t)(pt*6 + st)*64 + gf*16 + cf)*8) = vv;
  }
}

// ---------------- QK^T via MFMA, k-split over L ----------------
__global__ __launch_bounds__(64) void qk_mfma_k(const ushort* __restrict__ qb, const ushort* __restrict__ kb,
                                                float* __restrict__ P){
  int ks = blockIdx.x, bh = blockIdx.y;
  int b = bh >> 2, h = bh & 3;
  int lane = threadIdx.x, g16 = lane>>4, c16 = lane&15;
  const ushort* qbase = qb + ((size_t)b*C0 + h*CHN)*L;
  const ushort* kbse  = kb + ((size_t)b*C0 + h*CHN)*L;
  f32x4 acc[3][3];
  #pragma unroll
  for (int i=0;i<3;++i)
    #pragma unroll
    for (int j=0;j<3;++j){ f32x4 z={0.f,0.f,0.f,0.f}; acc[i][j]=z; }
  int k0 = ks * (L/KSPL);
  for (int kk=0; kk<(L/KSPL)/32; ++kk){
    int kb2 = k0 + kk*32;
    bf16x8 af[3], bv[3];
    #pragma unroll
    for (int i=0;i<3;++i){
      af[i] = ld_bf8(qbase + (size_t)(i*16+c16)*L + kb2 + g16*8);
      bv[i] = ld_bf8(kbse  + (size_t)(i*16+c16)*L + kb2 + g16*8);
    }
    #pragma unroll
    for (int mi=0;mi<3;++mi)
      #pragma unroll
      for (int ni=0;ni<3;++ni)
        acc[mi][ni] = mfma16(af[mi], bv[ni], acc[mi][ni]);
  }
  float* Pp = P + ((size_t)ks*(BATCH*NH) + bh)*CHN*CHN;
  #pragma unroll
  for (int mi=0;mi<3;++mi)
    #pragma unroll
    for (int ni=0;ni<3;++ni)
      #pragma unroll
      for (int r=0;r<4;++r){
        int m = mi*16 + g16*4 + r, n = ni*16 + c16;
        Pp[m*CHN + n] = acc[mi][ni][r];
      }
}

// ---------------- Pp-reduce + softmax + gating + Wca modulation ----------------
__global__ __launch_bounds__(64) void gating_k(const float* __restrict__ Pp, const float* __restrict__ qss,
                         const float* __restrict__ kss, const float* __restrict__ temp,
                         const float* __restrict__ Wca, float* __restrict__ attnF){
  int blk = blockIdx.x;
  int c  = blk % CHN; int bh = blk / CHN;
  int h  = bh & 3, b = bh >> 2;
  int d  = threadIdx.x;
  bool act = (d < CHN);

  float sv = 0.f;
  if (act){
    const float* pr = Pp + (size_t)bh*CHN*CHN + c*CHN + d;
    for (int ks=0; ks<KSPL; ++ks) sv += pr[(size_t)ks*(BATCH*NH)*CHN*CHN];
  }

  float T  = temp[h];
  float nq = sqrtf(qss[b*C0 + h*CHN + c]);
  float rq = 1.f/fmaxf(nq, 1e-12f);
  float rk = 0.f;
  if (act){
    float nk = sqrtf(kss[b*C0 + h*CHN + d]);
    rk = 1.f/fmaxf(nk, 1e-12f);
  }
  float raw = act ? sv*rq*rk*T : -1e30f;

  float mx = raw;
  #pragma unroll
  for (int off=32; off>0; off>>=1) mx = fmaxf(mx, __shfl_xor(mx, off, 64));
  float e = act ? expf(raw - mx) : 0.f;
  float sum = e;
  #pragma unroll
  for (int off=32; off>0; off>>=1) sum += __shfl_xor(sum, off, 64);
  float a0 = e / sum;

  float r = fmaxf(raw, 0.f); r = r*r;
  float a1 = gelu_exact(r)*r;
  __shared__ float a1s[CHN];
  if (act) a1s[d] = a1;
  __syncthreads();

  if (!act) return;
  float s1 = 0.f, s2 = 0.f;
  const float* w1 = Wca + (size_t)d*CHN;
  const float* w2 = Wca + (size_t)(d+CHN)*CHN;
  #pragma unroll
  for (int j=0;j<CHN;++j){
    float aj = a1s[j];
    s1 = fmaf(w1[j], aj, s1);
    s2 = fmaf(w2[j], aj, s2);
  }
  attnF[((size_t)bh*CHN + c)*CHN + d] = a0*(1.f+s1) + s2;
}

// Mtf frag-packed
__global__ void mtf_k(const float* __restrict__ Wproj, const float* __restrict__ attnF,
                      ushort* __restrict__ Mtf){
  int idx = blockIdx.x*256 + threadIdx.x;
  if (idx >= BATCH*192*192) return;
  int j = idx & 7; int t = idx >> 3;
  int lane = t & 63; t >>= 6;
  int st = t % 6; t /= 6;
  int mt = t % 12; int b = t / 12;
  int o = mt*16 + (lane & 15);
  int d = st*32 + (lane >> 4)*8 + j;
  int h = d / CHN, dd = d % CHN;
  float s=0.f;
  for (int c=0;c<CHN;++c)
    s = fmaf(Wproj[(size_t)o*C0 + h*CHN + c],
             attnF[(((size_t)(b*NH+h))*CHN + c)*CHN + dd], s);
  Mtf[idx] = f2u(s);
}

// ---------------- GDFN dwconv + gelu gate -> frag-packed Gf, XCD-swizzled, XOR-LDS ----------------
__global__ __launch_bounds__(256) void ffn8f_k(const ushort* __restrict__ hidden, const float* __restrict__ w9,
                                               ushort* __restrict__ gf){
  __shared__ ushort lt[64][40];
  int xs = blockIdx.x;
  int chunk = ((xs & 7) << 5) | (xs >> 3);
  int st = blockIdx.y, b = blockIdx.z;
  int t = threadIdx.x;
  int c = t >> 3, xo = (t & 7)*8;
  int l0 = chunk*64;
  int y = l0 >> 7, px = (l0 & 127) + xo;
  int gc = st*32 + c;
  ushort o8[8];
  if (gc < HID){
    const ushort* i1 = hidden + ((size_t)b*HID2 + gc)*L;
    const ushort* i2 = i1 + (size_t)HID*L;
    float w1[9], w2[9];
    #pragma unroll
    for (int i=0;i<9;++i){ w1[i] = w9[gc*9+i]; w2[i] = w9[(HID+gc)*9+i]; }
    float v1[3][10], v2[3][10];
    #pragma unroll
    for (int r=0;r<3;++r){
      int yy = y + r - 1;
      if ((unsigned)yy >= IMG){
        #pragma unroll
        for (int j=0;j<10;++j){ v1[r][j]=0.f; v2[r][j]=0.f; }
      } else {
        const ushort* rp1 = i1 + yy*IMG + px;
        const ushort* rp2 = i2 + yy*IMG + px;
        uint4 c1 = *(const uint4*)rp1; const ushort* u1 = (const ushort*)&c1;
        uint4 c2 = *(const uint4*)rp2; const ushort* u2 = (const ushort*)&c2;
        #pragma unroll
        for (int j=0;j<8;++j){ v1[r][j+1] = u2f(u1[j]); v2[r][j+1] = u2f(u2[j]); }
        v1[r][0] = (px>0)   ? u2f(rp1[-1]) : 0.f;
        v1[r][9] = (px<120) ? u2f(rp1[8])  : 0.f;
        v2[r][0] = (px>0)   ? u2f(rp2[-1]) : 0.f;
        v2[r][9] = (px<120) ? u2f(rp2[8])  : 0.f;
      }
    }
    #pragma unroll
    for (int j=0;j<8;++j){
      float d1=0.f, d2=0.f;
      #pragma unroll
      for (int r=0;r<3;++r)
        #pragma unroll
        for (int dx=0;dx<3;++dx){
          d1 = fmaf(w1[r*3+dx], v1[r][j+dx], d1);
          d2 = fmaf(w2[r*3+dx], v2[r][j+dx], d2);
        }
      o8[j] = f2u(gelu_exact(d1)*d2);
    }
  } else {
    #pragma unroll
    for (int j=0;j<8;++j) o8[j] = 0;
  }
  #pragma unroll
  for (int j=0;j<8;++j){
    int row = xo + j;
    lt[row][c ^ (((row>>3)&3)<<3)] = o8[j];
  }
  __syncthreads();
  int ptl = t>>6, gfr = (t>>4)&3, cf = t&15;
  int rrow = ptl*16 + cf;
  int oct = gfr ^ ((rrow>>3)&3);
  uint4 vv = *(const uint4*)&lt[rrow][oct*8];
  int pt = (l0>>4) + ptl;
  *(uint4*)(gf + (size_t)b*512*L + ((size_t)(pt*16 + st)*64 + gfr*16 + cf)*8) = vv;
}

extern "C" void kernel_launch(void* const* d_in, const int* in_sizes, int n_in,
                              void* d_out, int out_size, void* d_ws, size_t ws_size,
                              hipStream_t stream){
  (void)in_sizes; (void)n_in; (void)out_size; (void)ws_size;
  const float* lr    = (const float*)d_in[0];
  const float* ref   = (const float*)d_in[1];
  const float* ln1w  = (const float*)d_in[2];
  const float* ln1b  = (const float*)d_in[3];
  const float* lnrw  = (const float*)d_in[4];
  const float* lnrb  = (const float*)d_in[5];
  const float* ln2w  = (const float*)d_in[6];
  const float* ln2b  = (const float*)d_in[7];
  const float* Wq    = (const float*)d_in[8];
  const float* qdw   = (const float*)d_in[9];
  const float* Wkv   = (const float*)d_in[10];
  const float* kvdw  = (const float*)d_in[11];
  const float* Wproj = (const float*)d_in[12];
  const float* Wca   = (const float*)d_in[13];
  const float* temp  = (const float*)d_in[14];
  const float* Wpin  = (const float*)d_in[15];
  const float* ffndw = (const float*)d_in[16];
  const float* Wpout = (const float*)d_in[17];
  float* out = (float*)d_out;

  char* ws = (char*)d_ws;
  size_t off = 0;
  auto alloc = [&](size_t bytes)->void*{ void* p = ws + off; off += (bytes + 255) & ~(size_t)255; return p; };

  ushort* Aqf    = (ushort*)alloc((size_t)192*192*2);
  ushort* Akvf   = (ushort*)alloc((size_t)384*192*2);
  ushort* Apinf  = (ushort*)alloc((size_t)1024*192*2);
  ushort* Apoutf = (ushort*)alloc((size_t)192*512*2);
  ushort* Mtf    = (ushort*)alloc((size_t)BATCH*192*192*2);
  float* Aqv  = (float*)alloc(192*4);   float* Bqv  = (float*)alloc(192*4);
  float* Akvv = (float*)alloc(384*4);   float* Bkvv = (float*)alloc(384*4);
  float* Apinv= (float*)alloc(1024*4);  float* Bpinv= (float*)alloc(1024*4);
  float* mu_lr = (float*)alloc((size_t)BL*4);  float* rs_lr = (float*)alloc((size_t)BL*4);
  float* mu_rf = (float*)alloc((size_t)BL*4);  float* rs_rf = (float*)alloc((size_t)BL*4);
  // zero-init region: qss|kss|sum_o|ssq_o contiguous (66304 floats)
  float* qss   = (float*)alloc((size_t)BATCH*C0*4);
  float* kss   = (float*)alloc((size_t)BATCH*C0*4);
  float* sum_o = (float*)alloc((size_t)BL*4);
  float* ssq_o = (float*)alloc((size_t)BL*4);
  float* attnF = (float*)alloc((size_t)BATCH*NH*CHN*CHN*4);
  char*  pool  = (char*)alloc((size_t)113246208);   // 108 MiB

  // region map:
  ushort* LRf    = (ushort*)(pool);                    // [0, 12.58M)   live until proj done
  ushort* REFf   = (ushort*)(pool + 12582912);         // [12.58, 25.17) dead after qkv GEMM
  ushort* q_pre  = (ushort*)(pool + 25165824);         // [25.17, 37.75) dead after dwall
  ushort* kv_pre = (ushort*)(pool + 37748736);         // [37.75, 62.91) dead after dwall
  ushort* qb     = (ushort*)(pool + 62914560);         // [62.91, 75.50) dead after qk
  ushort* kvb_k  = (ushort*)(pool + 75497472);         // [75.50, 88.08) dead after qk
  ushort* Vf     = (ushort*)(pool + 88080384);         // [88.08, 100.66) dead after proj
  float*  Pp     = (float*) (pool + 12582912);         // 9.44M over REFf (written by qk)
  ushort* OUTf   = (ushort*)(pool + 66846720);         // [66.85, 79.43) over qb/kvb_k (dead post-qk)
  ushort* hidden = (ushort*)(pool);                    // [0, 66.85) over LRf..kv_pre (dead post-proj)
  ushort* Gf     = (ushort*)(pool + 79429632);         // [79.43, 112.98) over kvb_k tail+Vf (dead post-proj)

  // unified prep: weight packs + prepab + zero-init + LN stats/mirrors
  prep_all_k<<<2106,256,0,stream>>>(Wq, ln1w, ln1b, Aqf, Aqv, Bqv,
                                    Wkv, lnrw, lnrb, Akvf, Akvv, Bkvv,
                                    Wpin, ln2w, ln2b, Apinf, Apinv, Bpinv,
                                    Wpout, Apoutf,
                                    qss,
                                    lr, ref, mu_lr, rs_lr, mu_rf, rs_rf, LRf, REFf);

  // merged fused LN + 1x1 conv GEMMs (q + kv in one launch)
  gemmqkv_k<<<dim3(256,9),256,0,stream>>>(Aqf, Akvf, LRf, REFf,
      mu_lr, rs_lr, mu_rf, rs_rf, Aqv, Bqv, Akvv, Bkvv, q_pre, kv_pre);

  // merged depthwise: q+k row-major (+ss) and v frag-packed
  dwall_k<<<9216,256,0,stream>>>(q_pre, kv_pre, qdw, kvdw, qb, kvb_k, qss, kss, Vf);

  // attention core
  qk_mfma_k<<<dim3(KSPL, BATCH*NH),64,0,stream>>>(qb, kvb_k, Pp);
  gating_k<<<BATCH*NH*CHN,64,0,stream>>>(Pp, qss, kss, temp, Wca, attnF);
  mtf_k<<<288,256,0,stream>>>(Wproj, attnF, Mtf);

  // lr2 = u2f(LRf) + Mt.v -> OUTf (bf16 frag) + LN-stat atomics (no f32 traffic)
  gemm5_k<4,1,6,128><<<dim3(256,3),256,0,stream>>>(Mtf, 192*192, Vf, (size_t)C0*L,
      nullptr, nullptr, nullptr, nullptr, LRf, nullptr, 192, 192, OUTf, sum_o, ssq_o);

  // GDFN: pin with inline LN-from-raw-stats
  gemm5_k<6,2,6,128><<<dim3(256,8),256,0,stream>>>(Apinf, 0, OUTf, (size_t)C0*L,
      sum_o, ssq_o, Apinv, Bpinv, nullptr, hidden, 1020, 1020, nullptr, nullptr, nullptr);
  ffn8f_k<<<dim3(256,16,2),256,0,stream>>>(hidden, ffndw, Gf);

  // final: out = u2f(OUTf) + Wpout.g
  gemm5_k<5,1,16,128><<<dim3(256,3),256,0,stream>>>(Apoutf, 0, Gf, (size_t)512*L,
      nullptr, nullptr, nullptr, nullptr, nullptr, out, 192, 192, OUTf, nullptr, nullptr);
}